// Round 9
// baseline (682.740 us; speedup 1.0000x reference)
//
#include <hip/hip_runtime.h>
#include <hip/hip_bf16.h>
#include <math.h>

#define B_ 32
#define N_ 784
#define C_ 576
#define H_ 28
#define W_ 28
#define HEADS_ 8
#define HD_ 72
#define AGENT_ 49
#define M_ (B_ * N_)            // 25088
#define KTOT_ 5184              // 576 silu + 576*8 spline
#define QKVW_ 1728
#define SCALE_ 0.11785113019775793f

// swizzled LDS addressing: stride 32 elems (64 B), 16B chunks XOR-swizzled
// (T2: write and read use the SAME involution; verified round 7/8: conflicts = 0)
#define SWZ(row, chunk) (((row) << 5) + ((((chunk) ^ (((row) >> 1) & 3))) << 3))

typedef unsigned short ushort_t;
typedef __attribute__((ext_vector_type(8))) unsigned short u16x8;
typedef __attribute__((ext_vector_type(8))) __bf16 bf16x8;
typedef __attribute__((ext_vector_type(4))) float f32x4;
typedef __attribute__((ext_vector_type(4))) unsigned u32x4;

__device__ __forceinline__ ushort_t f2bf(float f) {
  union { float f; unsigned u; } v; v.f = f;
  unsigned r = v.u + 0x7fffu + ((v.u >> 16) & 1u);
  return (ushort_t)(r >> 16);
}
__device__ __forceinline__ float bf2f(ushort_t u) {
  union { unsigned u; float f; } v; v.u = ((unsigned)u) << 16;
  return v.f;
}
__device__ __forceinline__ unsigned pack2(float lo, float hi) {
  __bf16 a = (__bf16)lo, b = (__bf16)hi;
  unsigned short ua = __builtin_bit_cast(unsigned short, a);
  unsigned short ub = __builtin_bit_cast(unsigned short, b);
  return (unsigned)ua | ((unsigned)ub << 16);
}

// ---------------- converts / packs ----------------
__global__ __launch_bounds__(256) void convert_x_kernel(
    const float* __restrict__ x, ushort_t* __restrict__ xbf) {
  const int total8 = M_ * C_ / 8;
  for (int i = blockIdx.x * 256 + threadIdx.x; i < total8; i += gridDim.x * 256) {
    f32x4 a = *(const f32x4*)(x + i * 8);
    f32x4 b = *(const f32x4*)(x + i * 8 + 4);
    u16x8 o;
    o[0]=f2bf(a[0]); o[1]=f2bf(a[1]); o[2]=f2bf(a[2]); o[3]=f2bf(a[3]);
    o[4]=f2bf(b[0]); o[5]=f2bf(b[1]); o[6]=f2bf(b[2]); o[7]=f2bf(b[3]);
    *(u16x8*)(xbf + i * 8) = o;
  }
}

__global__ __launch_bounds__(256) void pack_w_kernel(
    const float* __restrict__ Wq, const float* __restrict__ Wkv,
    ushort_t* __restrict__ wbf) {
  int total = QKVW_ * C_;
  for (int i = blockIdx.x * 256 + threadIdx.x; i < total; i += gridDim.x * 256) {
    int j = i / C_, k = i % C_;
    float v = (j < C_) ? Wq[(size_t)j * C_ + k] : Wkv[(size_t)(j - C_) * C_ + k];
    wbf[i] = f2bf(v);
  }
}

__global__ __launch_bounds__(256) void pack_b_kernel(
    const float* __restrict__ base_w, const float* __restrict__ spline_w,
    const float* __restrict__ spline_s, ushort_t* __restrict__ bpackb) {
  int o = blockIdx.x;
  for (int j = threadIdx.x; j < KTOT_; j += 256) {
    float v;
    if (j < C_) {
      v = base_w[(size_t)o * C_ + j];
    } else {
      int jj = j - C_;
      int i = jj >> 3, kk = jj & 7;
      v = spline_w[((size_t)o * C_ + i) * 8 + kk] * spline_s[(size_t)o * C_ + i];
    }
    bpackb[(size_t)o * KTOT_ + j] = f2bf(v);
  }
}

// ---------------- bias precompute ----------------
__device__ __forceinline__ float bilerp7(const float* __restrict__ Bsrc, int y, int x) {
  float sy = y * 0.25f - 0.375f;
  float sx = x * 0.25f - 0.375f;
  float fy0 = floorf(sy), fx0 = floorf(sx);
  int y0 = (int)fy0, x0 = (int)fx0;
  float fy = sy - fy0, fx = sx - fx0;
  int y0c = min(6, max(0, y0)), y1c = min(6, max(0, y0 + 1));
  int x0c = min(6, max(0, x0)), x1c = min(6, max(0, x0 + 1));
  float v00 = Bsrc[y0c * 7 + x0c], v01 = Bsrc[y0c * 7 + x1c];
  float v10 = Bsrc[y1c * 7 + x0c], v11 = Bsrc[y1c * 7 + x1c];
  return (1.f - fy) * ((1.f - fx) * v00 + fx * v01)
       + fy * ((1.f - fx) * v10 + fx * v11);
}

__global__ __launch_bounds__(256) void bias_kernel(
    const float* __restrict__ an_bias, const float* __restrict__ na_bias,
    const float* __restrict__ ah_bias, const float* __restrict__ aw_bias,
    const float* __restrict__ ha_bias, const float* __restrict__ wa_bias,
    float* __restrict__ abias, float* __restrict__ qbias) {
  int idx = blockIdx.x * 256 + threadIdx.x;
  if (idx >= HEADS_ * AGENT_ * N_) return;
  int n = idx % N_;
  int ha = idx / N_;
  int h = ha / AGENT_, a = ha % AGENT_;
  int y = n / W_, x = n % W_;
  float pb1 = bilerp7(an_bias + (size_t)ha * 49, y, x);
  float pb2 = ah_bias[ha * H_ + y] + aw_bias[ha * W_ + x];
  abias[(size_t)ha * N_ + n] = pb1 + pb2;
  float ab1 = bilerp7(na_bias + (size_t)ha * 49, y, x);
  float ab2 = ha_bias[(h * H_ + y) * AGENT_ + a] + wa_bias[(h * W_ + x) * AGENT_ + a];
  qbias[((size_t)h * N_ + n) * AGENT_ + a] = ab1 + ab2;
}

// ---------------- MFMA GEMM: qkv (256 thr, 128x96 tile, dbuf, swizzled LDS) --
// grid: 3528 = 196 row-tiles x 18 col-tiles (col fastest); 3528 = 8*441
__global__ __launch_bounds__(256, 4) void mfma_qkv_kernel(
    const ushort_t* __restrict__ A, const ushort_t* __restrict__ Bt,
    ushort_t* __restrict__ out) {
  __shared__ ushort_t Asl[2][128 * 32];
  __shared__ ushort_t Bsl[2][96 * 32];
  const int tid = threadIdx.x;
  const int lane = tid & 63, wid = tid >> 6;
  const int wm = wid >> 1, wn = wid & 1;
  const int l16 = lane & 15, lq = lane >> 4;

  int lin = blockIdx.x;
  int xcd = lin & 7;
  int wg = xcd * 441 + (lin >> 3);
  const int m0 = (wg / 18) * 128, n0 = (wg % 18) * 96;

  const int rA = tid >> 2, hA = tid & 3;     // A rows rA and rA+64
  const int rB0 = tid >> 2, cB0 = tid & 3;   // B rows 0..63
  const int rB1 = 64 + (tid >> 2);           // B rows 64..95 (tid<128)
  const bool hasB1 = tid < 128;

  const ushort_t* arow0 = A + (size_t)(m0 + rA) * C_ + hA * 8;
  const ushort_t* arow1 = arow0 + (size_t)64 * C_;
  const ushort_t* brow0 = Bt + (size_t)(n0 + rB0) * C_ + cB0 * 8;
  const ushort_t* brow1 = Bt + (size_t)(n0 + rB1) * C_ + cB0 * 8;

  const int aWo0 = SWZ(rA, hA), aWo1 = SWZ(rA + 64, hA);
  const int b0Wo = SWZ(rB0, cB0), b1Wo = SWZ(rB1, cB0);

  f32x4 acc[4][3] = {};
  u16x8 ar0, ar1, br0, br1;

  ar0 = *(const u16x8*)(arow0);
  ar1 = *(const u16x8*)(arow1);
  br0 = *(const u16x8*)(brow0);
  if (hasB1) br1 = *(const u16x8*)(brow1);
  *(u16x8*)&Asl[0][aWo0] = ar0;
  *(u16x8*)&Asl[0][aWo1] = ar1;
  *(u16x8*)&Bsl[0][b0Wo] = br0;
  if (hasB1) *(u16x8*)&Bsl[0][b1Wo] = br1;
  ar0 = *(const u16x8*)(arow0 + 32);
  ar1 = *(const u16x8*)(arow1 + 32);
  br0 = *(const u16x8*)(brow0 + 32);
  if (hasB1) br1 = *(const u16x8*)(brow1 + 32);
  __syncthreads();

  const int NSTEP = C_ / 32;   // 18
  for (int s = 0; s < NSTEP; ++s) {
    const int cur = s & 1;
    bf16x8 af[4], bfr[3];
    #pragma unroll
    for (int fm = 0; fm < 4; ++fm)
      af[fm] = *(const bf16x8*)&Asl[cur][SWZ(wm * 64 + fm * 16 + l16, lq)];
    #pragma unroll
    for (int fn = 0; fn < 3; ++fn)
      bfr[fn] = *(const bf16x8*)&Bsl[cur][SWZ(wn * 48 + fn * 16 + l16, lq)];
    #pragma unroll
    for (int fm = 0; fm < 4; ++fm)
      #pragma unroll
      for (int fn = 0; fn < 3; ++fn)
        acc[fm][fn] = __builtin_amdgcn_mfma_f32_16x16x32_bf16(
            af[fm], bfr[fn], acc[fm][fn], 0, 0, 0);
    if (s + 1 < NSTEP) {
      const int nxt = cur ^ 1;
      *(u16x8*)&Asl[nxt][aWo0] = ar0;
      *(u16x8*)&Asl[nxt][aWo1] = ar1;
      *(u16x8*)&Bsl[nxt][b0Wo] = br0;
      if (hasB1) *(u16x8*)&Bsl[nxt][b1Wo] = br1;
      if (s + 2 < NSTEP) {
        const int kl = (s + 2) * 32;
        ar0 = *(const u16x8*)(arow0 + kl);
        ar1 = *(const u16x8*)(arow1 + kl);
        br0 = *(const u16x8*)(brow0 + kl);
        if (hasB1) br1 = *(const u16x8*)(brow1 + kl);
      }
    }
    __syncthreads();
  }
  #pragma unroll
  for (int fm = 0; fm < 4; ++fm) {
    #pragma unroll
    for (int fn = 0; fn < 3; ++fn) {
      int col = n0 + wn * 48 + fn * 16 + l16;
      #pragma unroll
      for (int r2 = 0; r2 < 4; ++r2) {
        int row = m0 + wm * 64 + fm * 16 + lq * 4 + r2;
        out[(size_t)row * QKVW_ + col] = f2bf(acc[fm][fn][r2]);
      }
    }
  }
}

// ---------------- KAN A-operand generation (funnel-shift placement) --------
__device__ __forceinline__ u32x4 basesPack(float xv) {
  float s = __fmaf_rn(xv, 2.5f, 5.5f);
  float tf = floorf(s);
  int t = (int)tf;
  float u = s - tf;
  float u2 = u * u, u3 = u2 * u, um = 1.f - u;
  float p0 = u3 * (1.f / 6.f);
  float p1 = __fmaf_rn(u3, -0.5f, __fmaf_rn(u2, 0.5f, __fmaf_rn(u, 0.5f, 1.f / 6.f)));
  float p2 = __fmaf_rn(u3, 0.5f, __fmaf_rn(u2, -1.f, 2.f / 3.f));
  float p3 = um * um * um * (1.f / 6.f);
  unsigned lo = pack2(p3, p2);          // slot0=p3, slot1=p2
  unsigned hi = pack2(p1, p0);          // slot2=p1, slot3=p0
  unsigned long long packed = ((unsigned long long)hi << 32) | (unsigned long long)lo;
  int sh = t - 3;
  int ba = sh << 4;
  unsigned long long shl_lo = packed << (ba & 63);
  unsigned long long shr_sp = packed >> ((64 - ba) & 63);
  unsigned long long shl_hi = packed << ((ba - 64) & 63);
  unsigned long long shr_ng = packed >> ((-ba) & 63);
  unsigned long long Olo = (sh < 0) ? shr_ng : ((sh < 4) ? shl_lo : 0ull);
  unsigned long long Ohi = (sh <= 0) ? 0ull : ((sh < 4) ? shr_sp : shl_hi);
  if (t < 0 || t > 10) { Olo = 0ull; Ohi = 0ull; }
  u32x4 o;
  o[0] = (unsigned)Olo; o[1] = (unsigned)(Olo >> 32);
  o[2] = (unsigned)Ohi; o[3] = (unsigned)(Ohi >> 32);
  return o;
}

__device__ __forceinline__ u32x4 siluPack(const float* xv) {
  u32x4 o;
  #pragma unroll
  for (int e = 0; e < 4; ++e) {
    float v0 = xv[2 * e], v1 = xv[2 * e + 1];
    float s0 = v0 / (1.f + __expf(-v0));
    float s1 = v1 / (1.f + __expf(-v1));
    o[e] = pack2(s0, s1);
  }
  return o;
}

// ---------------- KAN MFMA GEMM (256 thr, 128x96 tile, dbuf, swizzled LDS) --
// grid: 1176 = 196 row-tiles x 6 col-tiles (col fastest); 1176 = 8*147
__global__ __launch_bounds__(256, 4) void kan_mfma_kernel(
    const float* __restrict__ xf, const ushort_t* __restrict__ Bt,
    float* __restrict__ out) {
  __shared__ ushort_t Asl[2][128 * 32];
  __shared__ ushort_t Bsl[2][96 * 32];
  const int tid = threadIdx.x;
  const int lane = tid & 63, wid = tid >> 6;
  const int wm = wid >> 1, wn = wid & 1;
  const int l16 = lane & 15, lq = lane >> 4;

  int lin = blockIdx.x;
  int xcd = lin & 7;
  int wg = xcd * 147 + (lin >> 3);
  const int m0 = (wg / 6) * 128, n0 = (wg % 6) * 96;

  const int rA = tid >> 2, hA = tid & 3;
  const int rB0 = tid >> 2, cB0 = tid & 3;
  const int rB1 = 64 + (tid >> 2);
  const bool hasB1 = tid < 128;

  const float* xfr0 = xf + (size_t)(m0 + rA) * C_;
  const float* xfr1 = xfr0 + (size_t)64 * C_;
  const ushort_t* brow0 = Bt + (size_t)(n0 + rB0) * KTOT_ + cB0 * 8;
  const ushort_t* brow1 = Bt + (size_t)(n0 + rB1) * KTOT_ + cB0 * 8;

  const int aWo0 = SWZ(rA, hA), aWo1 = SWZ(rA + 64, hA);
  const int b0Wo = SWZ(rB0, cB0), b1Wo = SWZ(rB1, cB0);

  f32x4 acc[4][3] = {};
  float xv0[8], xv1[8];
  u16x8 br0, br1;

  // step 0 load (silu region: 8 floats per A-half)
  {
    f32x4 a = *(const f32x4*)(xfr0 + hA * 8);
    f32x4 b = *(const f32x4*)(xfr0 + hA * 8 + 4);
    xv0[0]=a[0]; xv0[1]=a[1]; xv0[2]=a[2]; xv0[3]=a[3];
    xv0[4]=b[0]; xv0[5]=b[1]; xv0[6]=b[2]; xv0[7]=b[3];
    f32x4 c = *(const f32x4*)(xfr1 + hA * 8);
    f32x4 d = *(const f32x4*)(xfr1 + hA * 8 + 4);
    xv1[0]=c[0]; xv1[1]=c[1]; xv1[2]=c[2]; xv1[3]=c[3];
    xv1[4]=d[0]; xv1[5]=d[1]; xv1[6]=d[2]; xv1[7]=d[3];
  }
  br0 = *(const u16x8*)(brow0);
  if (hasB1) br1 = *(const u16x8*)(brow1);
  *(u32x4*)&Asl[0][aWo0] = siluPack(xv0);
  *(u32x4*)&Asl[0][aWo1] = siluPack(xv1);
  *(u16x8*)&Bsl[0][b0Wo] = br0;
  if (hasB1) *(u16x8*)&Bsl[0][b1Wo] = br1;
  // step 1 load
  {
    f32x4 a = *(const f32x4*)(xfr0 + 32 + hA * 8);
    f32x4 b = *(const f32x4*)(xfr0 + 32 + hA * 8 + 4);
    xv0[0]=a[0]; xv0[1]=a[1]; xv0[2]=a[2]; xv0[3]=a[3];
    xv0[4]=b[0]; xv0[5]=b[1]; xv0[6]=b[2]; xv0[7]=b[3];
    f32x4 c = *(const f32x4*)(xfr1 + 32 + hA * 8);
    f32x4 d = *(const f32x4*)(xfr1 + 32 + hA * 8 + 4);
    xv1[0]=c[0]; xv1[1]=c[1]; xv1[2]=c[2]; xv1[3]=c[3];
    xv1[4]=d[0]; xv1[5]=d[1]; xv1[6]=d[2]; xv1[7]=d[3];
  }
  br0 = *(const u16x8*)(brow0 + 32);
  if (hasB1) br1 = *(const u16x8*)(brow1 + 32);
  __syncthreads();

  const int NSTEP = KTOT_ / 32;   // 162
  for (int s = 0; s < NSTEP; ++s) {
    const int cur = s & 1;
    bf16x8 af[4], bfr[3];
    #pragma unroll
    for (int fm = 0; fm < 4; ++fm)
      af[fm] = *(const bf16x8*)&Asl[cur][SWZ(wm * 64 + fm * 16 + l16, lq)];
    #pragma unroll
    for (int fn = 0; fn < 3; ++fn)
      bfr[fn] = *(const bf16x8*)&Bsl[cur][SWZ(wn * 48 + fn * 16 + l16, lq)];
    #pragma unroll
    for (int fm = 0; fm < 4; ++fm)
      #pragma unroll
      for (int fn = 0; fn < 3; ++fn)
        acc[fm][fn] = __builtin_amdgcn_mfma_f32_16x16x32_bf16(
            af[fm], bfr[fn], acc[fm][fn], 0, 0, 0);
    if (s + 1 < NSTEP) {
      const int nxt = cur ^ 1;
      const int kg = (s + 1) * 32;
      u32x4 a0, a1;
      if (kg < C_) { a0 = siluPack(xv0); a1 = siluPack(xv1); }
      else         { a0 = basesPack(xv0[0]); a1 = basesPack(xv1[0]); }
      *(u32x4*)&Asl[nxt][aWo0] = a0;
      *(u32x4*)&Asl[nxt][aWo1] = a1;
      *(u16x8*)&Bsl[nxt][b0Wo] = br0;
      if (hasB1) *(u16x8*)&Bsl[nxt][b1Wo] = br1;
      if (s + 2 < NSTEP) {
        const int kl = (s + 2) * 32;
        if (kl < C_) {
          f32x4 a = *(const f32x4*)(xfr0 + kl + hA * 8);
          f32x4 b = *(const f32x4*)(xfr0 + kl + hA * 8 + 4);
          xv0[0]=a[0]; xv0[1]=a[1]; xv0[2]=a[2]; xv0[3]=a[3];
          xv0[4]=b[0]; xv0[5]=b[1]; xv0[6]=b[2]; xv0[7]=b[3];
          f32x4 c = *(const f32x4*)(xfr1 + kl + hA * 8);
          f32x4 d = *(const f32x4*)(xfr1 + kl + hA * 8 + 4);
          xv1[0]=c[0]; xv1[1]=c[1]; xv1[2]=c[2]; xv1[3]=c[3];
          xv1[4]=d[0]; xv1[5]=d[1]; xv1[6]=d[2]; xv1[7]=d[3];
        } else {
          int i0 = ((kl - C_) >> 3) + hA;
          xv0[0] = xfr0[i0];
          xv1[0] = xfr1[i0];
        }
        br0 = *(const u16x8*)(brow0 + kl);
        if (hasB1) br1 = *(const u16x8*)(brow1 + kl);
      }
    }
    __syncthreads();
  }
  #pragma unroll
  for (int fm = 0; fm < 4; ++fm) {
    #pragma unroll
    for (int fn = 0; fn < 3; ++fn) {
      int col = n0 + wn * 48 + fn * 16 + l16;
      #pragma unroll
      for (int r2 = 0; r2 < 4; ++r2) {
        int row = m0 + wm * 64 + fm * 16 + lq * 4 + r2;
        out[(size_t)row * C_ + col] = acc[fm][fn][r2];
      }
    }
  }
}

// ---------------- agent pooling ----------------
__global__ __launch_bounds__(576) void agent_pool_kernel(
    const ushort_t* __restrict__ qkvb, float* __restrict__ agent) {
  int ba = blockIdx.x;
  int b = ba / AGENT_, a = ba % AGENT_;
  int ay = a / 7, ax = a % 7;
  int ch = threadIdx.x;
  float s = 0.f;
  #pragma unroll
  for (int i2 = 0; i2 < 4; ++i2)
    #pragma unroll
    for (int i4 = 0; i4 < 4; ++i4)
      s += bf2f(qkvb[((size_t)b * N_ + (ay * 4 + i2) * W_ + (ax * 4 + i4)) * QKVW_ + ch]);
  agent[(size_t)ba * C_ + ch] = s * 0.0625f;
}

// ---------------- agent attention v3: MFMA flash, one block per (b,h) -------
#define AKS_ 104
#define VTS_ 136
__global__ __launch_bounds__(256) void agent_attn_mfma_kernel(
    const float* __restrict__ agent, const ushort_t* __restrict__ qkvb,
    const float* __restrict__ abias, float* __restrict__ agent_v) {
  __shared__ ushort_t A_lds[64 * AKS_];
  __shared__ ushort_t K_lds[112 * AKS_];
  __shared__ ushort_t Vt_lds[80 * VTS_];
  __shared__ ushort_t P_lds[4][16 * VTS_];
  const int tid = threadIdx.x;
  const int lane = tid & 63, wid = tid >> 6;
  const int l16 = lane & 15, lq = lane >> 4;
  const int b = blockIdx.x >> 3, h = blockIdx.x & 7;

  for (int i = tid; i < 64 * AKS_; i += 256) A_lds[i] = 0;
  for (int i = tid; i < 112 * 32; i += 256) {
    int r = i >> 5, cc = 72 + (i & 31);
    K_lds[r * AKS_ + cc] = 0;
  }
  for (int i = tid; i < 80 * VTS_; i += 256) Vt_lds[i] = 0;
  for (int i = tid; i < 4 * 16 * 24; i += 256) {
    int w = i / (16 * 24), rest = i % (16 * 24);
    int r = rest / 24, cc = 112 + rest % 24;
    P_lds[w][r * VTS_ + cc] = 0;
  }
  for (int i = tid; i < AGENT_ * HD_; i += 256) {
    int a = i / HD_, d = i % HD_;
    A_lds[a * AKS_ + d] = f2bf(agent[((size_t)b * AGENT_ + a) * C_ + h * HD_ + d]);
  }

  int srow[4], scol[4]; bool sval[4];
  #pragma unroll
  for (int i = 0; i < 4; ++i) {
    int idx = tid + i * 256;
    srow[i] = idx / 9; scol[i] = idx % 9;
    sval[i] = idx < 1008;
  }
  const ushort_t* kbase = qkvb + (size_t)b * N_ * QKVW_ + C_ + h * HD_;
  const ushort_t* vbase = qkvb + (size_t)b * N_ * QKVW_ + 2 * C_ + h * HD_;

  u16x8 kreg[4], vreg[4];
  #pragma unroll
  for (int i = 0; i < 4; ++i) {
    if (sval[i]) {
      kreg[i] = *(const u16x8*)(kbase + (size_t)srow[i] * QKVW_ + scol[i] * 8);
      vreg[i] = *(const u16x8*)(vbase + (size_t)srow[i] * QKVW_ + scol[i] * 8);
    }
  }
  #pragma unroll
  for (int i = 0; i < 4; ++i) {
    if (sval[i]) {
      *(u16x8*)&K_lds[srow[i] * AKS_ + scol[i] * 8] = kreg[i];
      #pragma unroll
      for (int e = 0; e < 8; ++e)
        Vt_lds[(scol[i] * 8 + e) * VTS_ + srow[i]] = vreg[i][e];
    }
  }
  __syncthreads();

  float m_r[4] = {-1e30f, -1e30f, -1e30f, -1e30f};
  float l_r[4] = {};
  f32x4 O[5] = {};
  const float* bias_base[4];
  #pragma unroll
  for (int r = 0; r < 4; ++r) {
    int a = wid * 16 + lq * 4 + r;
    a = min(a, AGENT_ - 1);
    bias_base[r] = abias + ((size_t)h * AGENT_ + a) * N_;
  }

  for (int c = 0; c < 7; ++c) {
    if (c < 6) {
      const size_t off = (size_t)(c + 1) * 112 * QKVW_;
      #pragma unroll
      for (int i = 0; i < 4; ++i) {
        if (sval[i]) {
          kreg[i] = *(const u16x8*)(kbase + off + (size_t)srow[i] * QKVW_ + scol[i] * 8);
          vreg[i] = *(const u16x8*)(vbase + off + (size_t)srow[i] * QKVW_ + scol[i] * 8);
        }
      }
    }
    f32x4 sacc[7] = {};
    #pragma unroll
    for (int ks = 0; ks < 3; ++ks) {
      bf16x8 af = *(const bf16x8*)&A_lds[(wid * 16 + l16) * AKS_ + ks * 32 + lq * 8];
      #pragma unroll
      for (int nt = 0; nt < 7; ++nt) {
        bf16x8 bf = *(const bf16x8*)&K_lds[(nt * 16 + l16) * AKS_ + ks * 32 + lq * 8];
        sacc[nt] = __builtin_amdgcn_mfma_f32_16x16x32_bf16(af, bf, sacc[nt], 0, 0, 0);
      }
    }
    float cmax[4] = {-1e30f, -1e30f, -1e30f, -1e30f};
    const int nb = c * 112 + l16;
    #pragma unroll
    for (int nt = 0; nt < 7; ++nt)
      #pragma unroll
      for (int r = 0; r < 4; ++r) {
        float lg = sacc[nt][r] * SCALE_ + bias_base[r][nb + nt * 16];
        sacc[nt][r] = lg;
        cmax[r] = fmaxf(cmax[r], lg);
      }
    #pragma unroll
    for (int off = 1; off < 16; off <<= 1)
      #pragma unroll
      for (int r = 0; r < 4; ++r)
        cmax[r] = fmaxf(cmax[r], __shfl_xor(cmax[r], off));
    float scl[4], rs[4];
    #pragma unroll
    for (int r = 0; r < 4; ++r) {
      float nm = fmaxf(m_r[r], cmax[r]);
      scl[r] = __expf(m_r[r] - nm);
      m_r[r] = nm;
      rs[r] = 0.f;
    }
    #pragma unroll
    for (int nt = 0; nt < 7; ++nt)
      #pragma unroll
      for (int r = 0; r < 4; ++r) {
        float p = __expf(sacc[nt][r] - m_r[r]);
        rs[r] += p;
        P_lds[wid][(lq * 4 + r) * VTS_ + nt * 16 + l16] = f2bf(p);
      }
    #pragma unroll
    for (int off = 1; off < 16; off <<= 1)
      #pragma unroll
      for (int r = 0; r < 4; ++r)
        rs[r] += __shfl_xor(rs[r], off);
    #pragma unroll
    for (int r = 0; r < 4; ++r) l_r[r] = l_r[r] * scl[r] + rs[r];
    #pragma unroll
    for (int nt = 0; nt < 5; ++nt)
      #pragma unroll
      for (int r = 0; r < 4; ++r) O[nt][r] *= scl[r];
    #pragma unroll
    for (int ks = 0; ks < 4; ++ks) {
      bf16x8 pf = *(const bf16x8*)&P_lds[wid][l16 * VTS_ + ks * 32 + lq * 8];
      #pragma unroll
      for (int nt = 0; nt < 5; ++nt) {
        bf16x8 vf = *(const bf16x8*)&Vt_lds[(nt * 16 + l16) * VTS_ + ks * 32 + lq * 8];
        O[nt] = __builtin_amdgcn_mfma_f32_16x16x32_bf16(pf, vf, O[nt], 0, 0, 0);
      }
    }
    __syncthreads();
    if (c < 6) {
      #pragma unroll
      for (int i = 0; i < 4; ++i) {
        if (sval[i]) {
          *(u16x8*)&K_lds[srow[i] * AKS_ + scol[i] * 8] = kreg[i];
          #pragma unroll
          for (int e = 0; e < 8; ++e)
            Vt_lds[(scol[i] * 8 + e) * VTS_ + srow[i]] = vreg[i][e];
        }
      }
      __syncthreads();
    }
  }
  float inv[4];
  #pragma unroll
  for (int r = 0; r < 4; ++r) inv[r] = 1.f / l_r[r];
  #pragma unroll
  for (int nt = 0; nt < 5; ++nt) {
    int d = nt * 16 + l16;
    if (d >= HD_) continue;
    #pragma unroll
    for (int r = 0; r < 4; ++r) {
      int a = wid * 16 + lq * 4 + r;
      if (a < AGENT_)
        agent_v[(((size_t)b * HEADS_ + h) * AGENT_ + a) * HD_ + d] = O[nt][r] * inv[r];
    }
  }
}

// ---------------- q attention ----------------
__global__ __launch_bounds__(256) void q_attn_kernel(
    const ushort_t* __restrict__ qkvb, const float* __restrict__ agent,
    const float* __restrict__ agent_v, const float* __restrict__ qbias,
    float* __restrict__ xf) {
  __shared__ float ag_t[HD_ * 52];
  __shared__ float av_t[HD_ * 52];
  const int tid = threadIdx.x;
  const int h = blockIdx.y, b = blockIdx.z;
  for (int t = tid; t < AGENT_ * HD_; t += 256) {
    int a = t / HD_, d = t % HD_;
    ag_t[d * 52 + a] = agent[((size_t)b * AGENT_ + a) * C_ + h * HD_ + d];
    av_t[d * 52 + a] = agent_v[(((size_t)b * HEADS_ + h) * AGENT_ + a) * HD_ + d];
  }
  __syncthreads();
  const int n = blockIdx.x * 256 + tid;
  if (n >= N_) return;
  const ushort_t* qp = qkvb + ((size_t)b * N_ + n) * QKVW_ + h * HD_;
  const float* qb = qbias + ((size_t)h * N_ + n) * AGENT_;
  float lg[AGENT_];
  #pragma unroll
  for (int a = 0; a < AGENT_; ++a) lg[a] = qb[a];
  for (int d = 0; d < HD_; ++d) {
    float qd = bf2f(qp[d]) * SCALE_;
    #pragma unroll
    for (int a = 0; a < AGENT_; ++a) lg[a] += qd * ag_t[d * 52 + a];
  }
  float mx = -1e30f;
  #pragma unroll
  for (int a = 0; a < AGENT_; ++a) mx = fmaxf(mx, lg[a]);
  float s = 0.f;
  #pragma unroll
  for (int a = 0; a < AGENT_; ++a) { lg[a] = __expf(lg[a] - mx); s += lg[a]; }
  float inv = 1.f / s;
  #pragma unroll
  for (int a = 0; a < AGENT_; ++a) lg[a] *= inv;
  float* op = xf + ((size_t)b * N_ + n) * C_ + h * HD_;
  for (int d = 0; d < HD_; ++d) {
    float acc = 0.f;
    #pragma unroll
    for (int a = 0; a < AGENT_; ++a) acc += lg[a] * av_t[d * 52 + a];
    op[d] = acc;
  }
}

// ---------------- depthwise conv + BN + ReLU (2ch/thread, XCD swizzle) ------
__global__ __launch_bounds__(288) void dwc_kernel(
    const ushort_t* __restrict__ qkvb, const float* __restrict__ w,
    const float* __restrict__ bias, const float* __restrict__ gamma,
    const float* __restrict__ beta, const float* __restrict__ mean,
    const float* __restrict__ var, float* __restrict__ xf) {
  int lin = blockIdx.x;
  const int bn = (lin & 7) * 3136 + (lin >> 3);   // 25088 = 8*3136, bijective
  const int b = bn / N_, n = bn % N_;
  const int y = n / W_, x = n % W_;
  const int c0 = threadIdx.x * 2;
  float a0 = 0.f, a1 = 0.f;
  #pragma unroll
  for (int ky = 0; ky < 3; ++ky) {
    int yy = y + ky - 1;
    if (yy < 0 || yy >= H_) continue;
    #pragma unroll
    for (int kx = 0; kx < 3; ++kx) {
      int xx = x + kx - 1;
      if (xx < 0 || xx >= W_) continue;
      unsigned v = *(const unsigned*)(qkvb + ((size_t)b * N_ + yy * W_ + xx) * QKVW_ + 2 * C_ + c0);
      a0 += w[c0 * 9 + ky * 3 + kx] * bf2f((ushort_t)(v & 0xffffu));
      a1 += w[(c0 + 1) * 9 + ky * 3 + kx] * bf2f((ushort_t)(v >> 16));
    }
  }
  float s0 = gamma[c0] * rsqrtf(var[c0] + 1e-5f);
  float s1 = gamma[c0 + 1] * rsqrtf(var[c0 + 1] + 1e-5f);
  float r0 = fmaxf((a0 + bias[c0] - mean[c0]) * s0 + beta[c0], 0.f);
  float r1 = fmaxf((a1 + bias[c0 + 1] - mean[c0 + 1]) * s1 + beta[c0 + 1], 0.f);
  float2* xp = (float2*)&xf[(size_t)bn * C_ + c0];
  float2 old = *xp;
  old.x += r0; old.y += r1;
  *xp = old;
}

extern "C" void kernel_launch(void* const* d_in, const int* in_sizes, int n_in,
                              void* d_out, int out_size, void* d_ws, size_t ws_size,
                              hipStream_t stream) {
  const float* x        = (const float*)d_in[0];
  const float* Wq       = (const float*)d_in[3];
  const float* Wkv      = (const float*)d_in[4];
  const float* an_bias  = (const float*)d_in[5];
  const float* na_bias  = (const float*)d_in[6];
  const float* ah_bias  = (const float*)d_in[7];
  const float* aw_bias  = (const float*)d_in[8];
  const float* ha_bias  = (const float*)d_in[9];
  const float* wa_bias  = (const float*)d_in[10];
  const float* dwc_w    = (const float*)d_in[11];
  const float* dwc_b    = (const float*)d_in[12];
  const float* bn_gamma = (const float*)d_in[13];
  const float* bn_beta  = (const float*)d_in[14];
  const float* bn_mean  = (const float*)d_in[15];
  const float* bn_var   = (const float*)d_in[16];
  const float* base_w   = (const float*)d_in[17];
  const float* spline_w = (const float*)d_in[18];
  const float* spline_s = (const float*)d_in[19];

  char* ws = (char*)d_ws;
  ushort_t* qkvb   = (ushort_t*)(ws + 0);
  ushort_t* xbf    = (ushort_t*)(ws + 86704128);
  ushort_t* wbf    = (ushort_t*)(ws + 115605504);
  ushort_t* bpackb = (ushort_t*)(ws + 117596160);
  float* agent     = (float*)(ws + 123568128);
  float* agent_v   = (float*)(ws + 127180800);
  float* abias     = (float*)(ws + 130793472);
  float* qbias     = (float*)(ws + 132022784);
  float* xf        = (float*)(ws + 133252096);
  float* out       = (float*)d_out;

  convert_x_kernel<<<dim3(2048), dim3(256), 0, stream>>>(x, xbf);
  pack_w_kernel<<<dim3(1024), dim3(256), 0, stream>>>(Wq, Wkv, wbf);
  pack_b_kernel<<<dim3(C_), dim3(256), 0, stream>>>(base_w, spline_w, spline_s, bpackb);
  bias_kernel<<<dim3((HEADS_ * AGENT_ * N_ + 255) / 256), dim3(256), 0, stream>>>(
      an_bias, na_bias, ah_bias, aw_bias, ha_bias, wa_bias, abias, qbias);
  mfma_qkv_kernel<<<dim3(3528), dim3(256), 0, stream>>>(xbf, wbf, qkvb);
  agent_pool_kernel<<<dim3(B_ * AGENT_), dim3(C_), 0, stream>>>(qkvb, agent);
  agent_attn_mfma_kernel<<<dim3(B_ * HEADS_), dim3(256), 0, stream>>>(
      agent, qkvb, abias, agent_v);
  q_attn_kernel<<<dim3(4, HEADS_, B_), dim3(256), 0, stream>>>(
      qkvb, agent, agent_v, qbias, xf);
  dwc_kernel<<<dim3(M_), dim3(288), 0, stream>>>(
      qkvb, dwc_w, dwc_b, bn_gamma, bn_beta, bn_mean, bn_var, xf);
  kan_mfma_kernel<<<dim3(1176), dim3(256), 0, stream>>>(xf, bpackb, out);
}

// Round 10
// 630.515 us; speedup vs baseline: 1.0828x; 1.0828x over previous
//
#include <hip/hip_runtime.h>
#include <hip/hip_bf16.h>
#include <math.h>

#define B_ 32
#define N_ 784
#define C_ 576
#define H_ 28
#define W_ 28
#define HEADS_ 8
#define HD_ 72
#define AGENT_ 49
#define M_ (B_ * N_)            // 25088
#define KTOT_ 5184              // 576 silu + 576*8 spline
#define QKVW_ 1728
#define SCALE_ 0.11785113019775793f

// BK=64 swizzled LDS: row stride 64 elems (128 B); 16B chunks XOR'd by row&7.
// Read: 16 rows x same chunk -> 8 distinct chunk slots, 2-way (free, m136).
// Write: 8 rows x 8 chunks per wave -> every chunk slot once per row, minimum.
#define SWZ64(row, chunk) (((row) << 6) + ((((chunk) ^ ((row) & 7))) << 3))

typedef unsigned short ushort_t;
typedef __attribute__((ext_vector_type(8))) unsigned short u16x8;
typedef __attribute__((ext_vector_type(8))) __bf16 bf16x8;
typedef __attribute__((ext_vector_type(4))) float f32x4;
typedef __attribute__((ext_vector_type(4))) unsigned u32x4;

__device__ __forceinline__ ushort_t f2bf(float f) {
  union { float f; unsigned u; } v; v.f = f;
  unsigned r = v.u + 0x7fffu + ((v.u >> 16) & 1u);
  return (ushort_t)(r >> 16);
}
__device__ __forceinline__ float bf2f(ushort_t u) {
  union { unsigned u; float f; } v; v.u = ((unsigned)u) << 16;
  return v.f;
}
__device__ __forceinline__ unsigned pack2(float lo, float hi) {
  __bf16 a = (__bf16)lo, b = (__bf16)hi;
  unsigned short ua = __builtin_bit_cast(unsigned short, a);
  unsigned short ub = __builtin_bit_cast(unsigned short, b);
  return (unsigned)ua | ((unsigned)ub << 16);
}

// ---------------- converts / packs ----------------
__global__ __launch_bounds__(256) void convert_x_kernel(
    const float* __restrict__ x, ushort_t* __restrict__ xbf) {
  const int total8 = M_ * C_ / 8;
  for (int i = blockIdx.x * 256 + threadIdx.x; i < total8; i += gridDim.x * 256) {
    f32x4 a = *(const f32x4*)(x + i * 8);
    f32x4 b = *(const f32x4*)(x + i * 8 + 4);
    u16x8 o;
    o[0]=f2bf(a[0]); o[1]=f2bf(a[1]); o[2]=f2bf(a[2]); o[3]=f2bf(a[3]);
    o[4]=f2bf(b[0]); o[5]=f2bf(b[1]); o[6]=f2bf(b[2]); o[7]=f2bf(b[3]);
    *(u16x8*)(xbf + i * 8) = o;
  }
}

__global__ __launch_bounds__(256) void pack_w_kernel(
    const float* __restrict__ Wq, const float* __restrict__ Wkv,
    ushort_t* __restrict__ wbf) {
  int total = QKVW_ * C_;
  for (int i = blockIdx.x * 256 + threadIdx.x; i < total; i += gridDim.x * 256) {
    int j = i / C_, k = i % C_;
    float v = (j < C_) ? Wq[(size_t)j * C_ + k] : Wkv[(size_t)(j - C_) * C_ + k];
    wbf[i] = f2bf(v);
  }
}

__global__ __launch_bounds__(256) void pack_b_kernel(
    const float* __restrict__ base_w, const float* __restrict__ spline_w,
    const float* __restrict__ spline_s, ushort_t* __restrict__ bpackb) {
  int o = blockIdx.x;
  for (int j = threadIdx.x; j < KTOT_; j += 256) {
    float v;
    if (j < C_) {
      v = base_w[(size_t)o * C_ + j];
    } else {
      int jj = j - C_;
      int i = jj >> 3, kk = jj & 7;
      v = spline_w[((size_t)o * C_ + i) * 8 + kk] * spline_s[(size_t)o * C_ + i];
    }
    bpackb[(size_t)o * KTOT_ + j] = f2bf(v);
  }
}

// ---------------- bias precompute ----------------
__device__ __forceinline__ float bilerp7(const float* __restrict__ Bsrc, int y, int x) {
  float sy = y * 0.25f - 0.375f;
  float sx = x * 0.25f - 0.375f;
  float fy0 = floorf(sy), fx0 = floorf(sx);
  int y0 = (int)fy0, x0 = (int)fx0;
  float fy = sy - fy0, fx = sx - fx0;
  int y0c = min(6, max(0, y0)), y1c = min(6, max(0, y0 + 1));
  int x0c = min(6, max(0, x0)), x1c = min(6, max(0, x0 + 1));
  float v00 = Bsrc[y0c * 7 + x0c], v01 = Bsrc[y0c * 7 + x1c];
  float v10 = Bsrc[y1c * 7 + x0c], v11 = Bsrc[y1c * 7 + x1c];
  return (1.f - fy) * ((1.f - fx) * v00 + fx * v01)
       + fy * ((1.f - fx) * v10 + fx * v11);
}

__global__ __launch_bounds__(256) void bias_kernel(
    const float* __restrict__ an_bias, const float* __restrict__ na_bias,
    const float* __restrict__ ah_bias, const float* __restrict__ aw_bias,
    const float* __restrict__ ha_bias, const float* __restrict__ wa_bias,
    float* __restrict__ abias, float* __restrict__ qbias) {
  int idx = blockIdx.x * 256 + threadIdx.x;
  if (idx >= HEADS_ * AGENT_ * N_) return;
  int n = idx % N_;
  int ha = idx / N_;
  int h = ha / AGENT_, a = ha % AGENT_;
  int y = n / W_, x = n % W_;
  float pb1 = bilerp7(an_bias + (size_t)ha * 49, y, x);
  float pb2 = ah_bias[ha * H_ + y] + aw_bias[ha * W_ + x];
  abias[(size_t)ha * N_ + n] = pb1 + pb2;
  float ab1 = bilerp7(na_bias + (size_t)ha * 49, y, x);
  float ab2 = ha_bias[(h * H_ + y) * AGENT_ + a] + wa_bias[(h * W_ + x) * AGENT_ + a];
  qbias[((size_t)h * N_ + n) * AGENT_ + a] = ab1 + ab2;
}

// ---------------- MFMA GEMM: qkv (8 waves, BK=64, dbuf, swizzled LDS) -------
// grid: 1764 = 196 row-tiles x 9 col-tiles (col fastest); 1764 = 8*220+4
__global__ __launch_bounds__(512, 4) void mfma_qkv_kernel(
    const ushort_t* __restrict__ A, const ushort_t* __restrict__ Bt,
    ushort_t* __restrict__ out) {
  __shared__ ushort_t Asl[2][128 * 64];   // 32 KB
  __shared__ ushort_t Bsl[2][192 * 64];   // 48 KB
  const int tid = threadIdx.x;
  const int lane = tid & 63, wid = tid >> 6;
  const int wm = wid >> 2, wn = wid & 3;
  const int l16 = lane & 15, lq = lane >> 4;

  int lin = blockIdx.x;
  const int q = 220, r = 4;          // 1764 = 8*220+4
  int xcd = lin & 7;
  int wg = (xcd < r ? xcd * (q + 1) : r * (q + 1) + (xcd - r) * q) + (lin >> 3);
  const int m0 = (wg / 9) * 128, n0 = (wg % 9) * 192;

  const int srowi = tid >> 3;        // 0..63
  const int chk = tid & 7;           // 0..7 (16B chunk within 64-elem window)

  const ushort_t* arow0 = A + (size_t)(m0 + srowi) * C_ + chk * 8;
  const ushort_t* arow1 = arow0 + (size_t)64 * C_;
  const ushort_t* brow0 = Bt + (size_t)(n0 + srowi) * C_ + chk * 8;
  const ushort_t* brow1 = brow0 + (size_t)64 * C_;
  const ushort_t* brow2 = brow0 + (size_t)128 * C_;

  const int aW0 = SWZ64(srowi, chk), aW1 = SWZ64(srowi + 64, chk);
  const int bW0 = SWZ64(srowi, chk), bW1 = SWZ64(srowi + 64, chk),
            bW2 = SWZ64(srowi + 128, chk);

  f32x4 acc[4][3] = {};
  u16x8 ar0, ar1, br0, br1, br2;

  // step0 load + write buf0
  ar0 = *(const u16x8*)(arow0);
  ar1 = *(const u16x8*)(arow1);
  br0 = *(const u16x8*)(brow0);
  br1 = *(const u16x8*)(brow1);
  br2 = *(const u16x8*)(brow2);
  *(u16x8*)&Asl[0][aW0] = ar0;
  *(u16x8*)&Asl[0][aW1] = ar1;
  *(u16x8*)&Bsl[0][bW0] = br0;
  *(u16x8*)&Bsl[0][bW1] = br1;
  *(u16x8*)&Bsl[0][bW2] = br2;
  // step1 load
  ar0 = *(const u16x8*)(arow0 + 64);
  ar1 = *(const u16x8*)(arow1 + 64);
  br0 = *(const u16x8*)(brow0 + 64);
  br1 = *(const u16x8*)(brow1 + 64);
  br2 = *(const u16x8*)(brow2 + 64);
  __syncthreads();

  const int NSTEP = C_ / 64;   // 9
  for (int s = 0; s < NSTEP; ++s) {
    const int cur = s & 1;
    #pragma unroll
    for (int ks = 0; ks < 2; ++ks) {
      bf16x8 af[4], bfr[3];
      #pragma unroll
      for (int fm = 0; fm < 4; ++fm)
        af[fm] = *(const bf16x8*)&Asl[cur][SWZ64(wm * 64 + fm * 16 + l16, ks * 4 + lq)];
      #pragma unroll
      for (int fn = 0; fn < 3; ++fn)
        bfr[fn] = *(const bf16x8*)&Bsl[cur][SWZ64(wn * 48 + fn * 16 + l16, ks * 4 + lq)];
      #pragma unroll
      for (int fm = 0; fm < 4; ++fm)
        #pragma unroll
        for (int fn = 0; fn < 3; ++fn)
          acc[fm][fn] = __builtin_amdgcn_mfma_f32_16x16x32_bf16(
              af[fm], bfr[fn], acc[fm][fn], 0, 0, 0);
    }
    if (s + 1 < NSTEP) {
      const int nxt = cur ^ 1;
      *(u16x8*)&Asl[nxt][aW0] = ar0;
      *(u16x8*)&Asl[nxt][aW1] = ar1;
      *(u16x8*)&Bsl[nxt][bW0] = br0;
      *(u16x8*)&Bsl[nxt][bW1] = br1;
      *(u16x8*)&Bsl[nxt][bW2] = br2;
      if (s + 2 < NSTEP) {
        const int kl = (s + 2) * 64;
        ar0 = *(const u16x8*)(arow0 + kl);
        ar1 = *(const u16x8*)(arow1 + kl);
        br0 = *(const u16x8*)(brow0 + kl);
        br1 = *(const u16x8*)(brow1 + kl);
        br2 = *(const u16x8*)(brow2 + kl);
      }
    }
    __syncthreads();
  }
  #pragma unroll
  for (int fm = 0; fm < 4; ++fm) {
    #pragma unroll
    for (int fn = 0; fn < 3; ++fn) {
      int col = n0 + wn * 48 + fn * 16 + l16;
      #pragma unroll
      for (int r2 = 0; r2 < 4; ++r2) {
        int row = m0 + wm * 64 + fm * 16 + lq * 4 + r2;
        out[(size_t)row * QKVW_ + col] = f2bf(acc[fm][fn][r2]);
      }
    }
  }
}

// ---------------- KAN A-operand generation (funnel-shift placement) --------
__device__ __forceinline__ u32x4 basesPack(float xv) {
  float s = __fmaf_rn(xv, 2.5f, 5.5f);
  float tf = floorf(s);
  int t = (int)tf;
  float u = s - tf;
  float u2 = u * u, u3 = u2 * u, um = 1.f - u;
  float p0 = u3 * (1.f / 6.f);
  float p1 = __fmaf_rn(u3, -0.5f, __fmaf_rn(u2, 0.5f, __fmaf_rn(u, 0.5f, 1.f / 6.f)));
  float p2 = __fmaf_rn(u3, 0.5f, __fmaf_rn(u2, -1.f, 2.f / 3.f));
  float p3 = um * um * um * (1.f / 6.f);
  unsigned lo = pack2(p3, p2);          // slot0=p3, slot1=p2
  unsigned hi = pack2(p1, p0);          // slot2=p1, slot3=p0
  unsigned long long packed = ((unsigned long long)hi << 32) | (unsigned long long)lo;
  int sh = t - 3;
  int ba = sh << 4;
  unsigned long long shl_lo = packed << (ba & 63);
  unsigned long long shr_sp = packed >> ((64 - ba) & 63);
  unsigned long long shl_hi = packed << ((ba - 64) & 63);
  unsigned long long shr_ng = packed >> ((-ba) & 63);
  unsigned long long Olo = (sh < 0) ? shr_ng : ((sh < 4) ? shl_lo : 0ull);
  unsigned long long Ohi = (sh <= 0) ? 0ull : ((sh < 4) ? shr_sp : shl_hi);
  if (t < 0 || t > 10) { Olo = 0ull; Ohi = 0ull; }
  u32x4 o;
  o[0] = (unsigned)Olo; o[1] = (unsigned)(Olo >> 32);
  o[2] = (unsigned)Ohi; o[3] = (unsigned)(Ohi >> 32);
  return o;
}

__device__ __forceinline__ u32x4 siluPack(const float* xv) {
  u32x4 o;
  #pragma unroll
  for (int e = 0; e < 4; ++e) {
    float v0 = xv[2 * e], v1 = xv[2 * e + 1];
    float s0 = v0 / (1.f + __expf(-v0));
    float s1 = v1 / (1.f + __expf(-v1));
    o[e] = pack2(s0, s1);
  }
  return o;
}

// ---------------- KAN MFMA GEMM (8 waves, BK=64, dbuf, swizzled LDS) --------
// grid: 588 = 196 row-tiles x 3 col-tiles (col fastest); 588 = 8*73+4
__global__ __launch_bounds__(512, 4) void kan_mfma_kernel(
    const float* __restrict__ xf, const ushort_t* __restrict__ Bt,
    float* __restrict__ out) {
  __shared__ ushort_t Asl[2][128 * 64];   // 32 KB
  __shared__ ushort_t Bsl[2][192 * 64];   // 48 KB
  const int tid = threadIdx.x;
  const int lane = tid & 63, wid = tid >> 6;
  const int wm = wid >> 2, wn = wid & 3;
  const int l16 = lane & 15, lq = lane >> 4;

  int lin = blockIdx.x;
  const int q = 73, r = 4;           // 588 = 8*73+4
  int xcd = lin & 7;
  int wg = (xcd < r ? xcd * (q + 1) : r * (q + 1) + (xcd - r) * q) + (lin >> 3);
  const int m0 = (wg / 3) * 128, n0 = (wg % 3) * 192;

  const int srowi = tid >> 3;        // 0..63
  const int chk = tid & 7;           // 0..7

  const float* xfr0 = xf + (size_t)(m0 + srowi) * C_;
  const float* xfr1 = xfr0 + (size_t)64 * C_;
  const ushort_t* brow0 = Bt + (size_t)(n0 + srowi) * KTOT_ + chk * 8;
  const ushort_t* brow1 = brow0 + (size_t)64 * KTOT_;
  const ushort_t* brow2 = brow0 + (size_t)128 * KTOT_;

  const int aW0 = SWZ64(srowi, chk), aW1 = SWZ64(srowi + 64, chk);
  const int bW0 = SWZ64(srowi, chk), bW1 = SWZ64(srowi + 64, chk),
            bW2 = SWZ64(srowi + 128, chk);

  f32x4 acc[4][3] = {};
  float xv0[8], xv1[8];
  u16x8 br0, br1, br2;

  // step0 load (silu region: 8 floats per slot at col chk*8)
  {
    f32x4 a = *(const f32x4*)(xfr0 + chk * 8);
    f32x4 b = *(const f32x4*)(xfr0 + chk * 8 + 4);
    xv0[0]=a[0]; xv0[1]=a[1]; xv0[2]=a[2]; xv0[3]=a[3];
    xv0[4]=b[0]; xv0[5]=b[1]; xv0[6]=b[2]; xv0[7]=b[3];
    f32x4 c = *(const f32x4*)(xfr1 + chk * 8);
    f32x4 d = *(const f32x4*)(xfr1 + chk * 8 + 4);
    xv1[0]=c[0]; xv1[1]=c[1]; xv1[2]=c[2]; xv1[3]=c[3];
    xv1[4]=d[0]; xv1[5]=d[1]; xv1[6]=d[2]; xv1[7]=d[3];
  }
  br0 = *(const u16x8*)(brow0);
  br1 = *(const u16x8*)(brow1);
  br2 = *(const u16x8*)(brow2);
  *(u32x4*)&Asl[0][aW0] = siluPack(xv0);
  *(u32x4*)&Asl[0][aW1] = siluPack(xv1);
  *(u16x8*)&Bsl[0][bW0] = br0;
  *(u16x8*)&Bsl[0][bW1] = br1;
  *(u16x8*)&Bsl[0][bW2] = br2;
  // step1 load
  {
    f32x4 a = *(const f32x4*)(xfr0 + 64 + chk * 8);
    f32x4 b = *(const f32x4*)(xfr0 + 64 + chk * 8 + 4);
    xv0[0]=a[0]; xv0[1]=a[1]; xv0[2]=a[2]; xv0[3]=a[3];
    xv0[4]=b[0]; xv0[5]=b[1]; xv0[6]=b[2]; xv0[7]=b[3];
    f32x4 c = *(const f32x4*)(xfr1 + 64 + chk * 8);
    f32x4 d = *(const f32x4*)(xfr1 + 64 + chk * 8 + 4);
    xv1[0]=c[0]; xv1[1]=c[1]; xv1[2]=c[2]; xv1[3]=c[3];
    xv1[4]=d[0]; xv1[5]=d[1]; xv1[6]=d[2]; xv1[7]=d[3];
  }
  br0 = *(const u16x8*)(brow0 + 64);
  br1 = *(const u16x8*)(brow1 + 64);
  br2 = *(const u16x8*)(brow2 + 64);
  __syncthreads();

  const int NSTEP = KTOT_ / 64;   // 81
  for (int s = 0; s < NSTEP; ++s) {
    const int cur = s & 1;
    #pragma unroll
    for (int ks = 0; ks < 2; ++ks) {
      bf16x8 af[4], bfr[3];
      #pragma unroll
      for (int fm = 0; fm < 4; ++fm)
        af[fm] = *(const bf16x8*)&Asl[cur][SWZ64(wm * 64 + fm * 16 + l16, ks * 4 + lq)];
      #pragma unroll
      for (int fn = 0; fn < 3; ++fn)
        bfr[fn] = *(const bf16x8*)&Bsl[cur][SWZ64(wn * 48 + fn * 16 + l16, ks * 4 + lq)];
      #pragma unroll
      for (int fm = 0; fm < 4; ++fm)
        #pragma unroll
        for (int fn = 0; fn < 3; ++fn)
          acc[fm][fn] = __builtin_amdgcn_mfma_f32_16x16x32_bf16(
              af[fm], bfr[fn], acc[fm][fn], 0, 0, 0);
    }
    if (s + 1 < NSTEP) {
      const int nxt = cur ^ 1;
      const int kg = (s + 1) * 64;
      u32x4 a0, a1;
      if (kg < C_) { a0 = siluPack(xv0); a1 = siluPack(xv1); }
      else         { a0 = basesPack(xv0[0]); a1 = basesPack(xv1[0]); }
      *(u32x4*)&Asl[nxt][aW0] = a0;
      *(u32x4*)&Asl[nxt][aW1] = a1;
      *(u16x8*)&Bsl[nxt][bW0] = br0;
      *(u16x8*)&Bsl[nxt][bW1] = br1;
      *(u16x8*)&Bsl[nxt][bW2] = br2;
      if (s + 2 < NSTEP) {
        const int kl = (s + 2) * 64;
        if (kl < C_) {
          f32x4 a = *(const f32x4*)(xfr0 + kl + chk * 8);
          f32x4 b = *(const f32x4*)(xfr0 + kl + chk * 8 + 4);
          xv0[0]=a[0]; xv0[1]=a[1]; xv0[2]=a[2]; xv0[3]=a[3];
          xv0[4]=b[0]; xv0[5]=b[1]; xv0[6]=b[2]; xv0[7]=b[3];
          f32x4 c = *(const f32x4*)(xfr1 + kl + chk * 8);
          f32x4 d = *(const f32x4*)(xfr1 + kl + chk * 8 + 4);
          xv1[0]=c[0]; xv1[1]=c[1]; xv1[2]=c[2]; xv1[3]=c[3];
          xv1[4]=d[0]; xv1[5]=d[1]; xv1[6]=d[2]; xv1[7]=d[3];
        } else {
          int i0 = ((kl - C_) >> 3) + chk;
          xv0[0] = xfr0[i0];
          xv1[0] = xfr1[i0];
        }
        br0 = *(const u16x8*)(brow0 + kl);
        br1 = *(const u16x8*)(brow1 + kl);
        br2 = *(const u16x8*)(brow2 + kl);
      }
    }
    __syncthreads();
  }
  #pragma unroll
  for (int fm = 0; fm < 4; ++fm) {
    #pragma unroll
    for (int fn = 0; fn < 3; ++fn) {
      int col = n0 + wn * 48 + fn * 16 + l16;
      #pragma unroll
      for (int r2 = 0; r2 < 4; ++r2) {
        int row = m0 + wm * 64 + fm * 16 + lq * 4 + r2;
        out[(size_t)row * C_ + col] = acc[fm][fn][r2];
      }
    }
  }
}

// ---------------- agent pooling ----------------
__global__ __launch_bounds__(576) void agent_pool_kernel(
    const ushort_t* __restrict__ qkvb, float* __restrict__ agent) {
  int ba = blockIdx.x;
  int b = ba / AGENT_, a = ba % AGENT_;
  int ay = a / 7, ax = a % 7;
  int ch = threadIdx.x;
  float s = 0.f;
  #pragma unroll
  for (int i2 = 0; i2 < 4; ++i2)
    #pragma unroll
    for (int i4 = 0; i4 < 4; ++i4)
      s += bf2f(qkvb[((size_t)b * N_ + (ay * 4 + i2) * W_ + (ax * 4 + i4)) * QKVW_ + ch]);
  agent[(size_t)ba * C_ + ch] = s * 0.0625f;
}

// ---------------- agent attention v3: MFMA flash, one block per (b,h) -------
#define AKS_ 104
#define VTS_ 136
__global__ __launch_bounds__(256) void agent_attn_mfma_kernel(
    const float* __restrict__ agent, const ushort_t* __restrict__ qkvb,
    const float* __restrict__ abias, float* __restrict__ agent_v) {
  __shared__ ushort_t A_lds[64 * AKS_];
  __shared__ ushort_t K_lds[112 * AKS_];
  __shared__ ushort_t Vt_lds[80 * VTS_];
  __shared__ ushort_t P_lds[4][16 * VTS_];
  const int tid = threadIdx.x;
  const int lane = tid & 63, wid = tid >> 6;
  const int l16 = lane & 15, lq = lane >> 4;
  const int b = blockIdx.x >> 3, h = blockIdx.x & 7;

  for (int i = tid; i < 64 * AKS_; i += 256) A_lds[i] = 0;
  for (int i = tid; i < 112 * 32; i += 256) {
    int r = i >> 5, cc = 72 + (i & 31);
    K_lds[r * AKS_ + cc] = 0;
  }
  for (int i = tid; i < 80 * VTS_; i += 256) Vt_lds[i] = 0;
  for (int i = tid; i < 4 * 16 * 24; i += 256) {
    int w = i / (16 * 24), rest = i % (16 * 24);
    int r = rest / 24, cc = 112 + rest % 24;
    P_lds[w][r * VTS_ + cc] = 0;
  }
  for (int i = tid; i < AGENT_ * HD_; i += 256) {
    int a = i / HD_, d = i % HD_;
    A_lds[a * AKS_ + d] = f2bf(agent[((size_t)b * AGENT_ + a) * C_ + h * HD_ + d]);
  }

  int srow[4], scol[4]; bool sval[4];
  #pragma unroll
  for (int i = 0; i < 4; ++i) {
    int idx = tid + i * 256;
    srow[i] = idx / 9; scol[i] = idx % 9;
    sval[i] = idx < 1008;
  }
  const ushort_t* kbase = qkvb + (size_t)b * N_ * QKVW_ + C_ + h * HD_;
  const ushort_t* vbase = qkvb + (size_t)b * N_ * QKVW_ + 2 * C_ + h * HD_;

  u16x8 kreg[4], vreg[4];
  #pragma unroll
  for (int i = 0; i < 4; ++i) {
    if (sval[i]) {
      kreg[i] = *(const u16x8*)(kbase + (size_t)srow[i] * QKVW_ + scol[i] * 8);
      vreg[i] = *(const u16x8*)(vbase + (size_t)srow[i] * QKVW_ + scol[i] * 8);
    }
  }
  #pragma unroll
  for (int i = 0; i < 4; ++i) {
    if (sval[i]) {
      *(u16x8*)&K_lds[srow[i] * AKS_ + scol[i] * 8] = kreg[i];
      #pragma unroll
      for (int e = 0; e < 8; ++e)
        Vt_lds[(scol[i] * 8 + e) * VTS_ + srow[i]] = vreg[i][e];
    }
  }
  __syncthreads();

  float m_r[4] = {-1e30f, -1e30f, -1e30f, -1e30f};
  float l_r[4] = {};
  f32x4 O[5] = {};
  const float* bias_base[4];
  #pragma unroll
  for (int r = 0; r < 4; ++r) {
    int a = wid * 16 + lq * 4 + r;
    a = min(a, AGENT_ - 1);
    bias_base[r] = abias + ((size_t)h * AGENT_ + a) * N_;
  }

  for (int c = 0; c < 7; ++c) {
    if (c < 6) {
      const size_t off = (size_t)(c + 1) * 112 * QKVW_;
      #pragma unroll
      for (int i = 0; i < 4; ++i) {
        if (sval[i]) {
          kreg[i] = *(const u16x8*)(kbase + off + (size_t)srow[i] * QKVW_ + scol[i] * 8);
          vreg[i] = *(const u16x8*)(vbase + off + (size_t)srow[i] * QKVW_ + scol[i] * 8);
        }
      }
    }
    f32x4 sacc[7] = {};
    #pragma unroll
    for (int ks = 0; ks < 3; ++ks) {
      bf16x8 af = *(const bf16x8*)&A_lds[(wid * 16 + l16) * AKS_ + ks * 32 + lq * 8];
      #pragma unroll
      for (int nt = 0; nt < 7; ++nt) {
        bf16x8 bf = *(const bf16x8*)&K_lds[(nt * 16 + l16) * AKS_ + ks * 32 + lq * 8];
        sacc[nt] = __builtin_amdgcn_mfma_f32_16x16x32_bf16(af, bf, sacc[nt], 0, 0, 0);
      }
    }
    float cmax[4] = {-1e30f, -1e30f, -1e30f, -1e30f};
    const int nb = c * 112 + l16;
    #pragma unroll
    for (int nt = 0; nt < 7; ++nt)
      #pragma unroll
      for (int r = 0; r < 4; ++r) {
        float lg = sacc[nt][r] * SCALE_ + bias_base[r][nb + nt * 16];
        sacc[nt][r] = lg;
        cmax[r] = fmaxf(cmax[r], lg);
      }
    #pragma unroll
    for (int off = 1; off < 16; off <<= 1)
      #pragma unroll
      for (int r = 0; r < 4; ++r)
        cmax[r] = fmaxf(cmax[r], __shfl_xor(cmax[r], off));
    float scl[4], rs[4];
    #pragma unroll
    for (int r = 0; r < 4; ++r) {
      float nm = fmaxf(m_r[r], cmax[r]);
      scl[r] = __expf(m_r[r] - nm);
      m_r[r] = nm;
      rs[r] = 0.f;
    }
    #pragma unroll
    for (int nt = 0; nt < 7; ++nt)
      #pragma unroll
      for (int r = 0; r < 4; ++r) {
        float p = __expf(sacc[nt][r] - m_r[r]);
        rs[r] += p;
        P_lds[wid][(lq * 4 + r) * VTS_ + nt * 16 + l16] = f2bf(p);
      }
    #pragma unroll
    for (int off = 1; off < 16; off <<= 1)
      #pragma unroll
      for (int r = 0; r < 4; ++r)
        rs[r] += __shfl_xor(rs[r], off);
    #pragma unroll
    for (int r = 0; r < 4; ++r) l_r[r] = l_r[r] * scl[r] + rs[r];
    #pragma unroll
    for (int nt = 0; nt < 5; ++nt)
      #pragma unroll
      for (int r = 0; r < 4; ++r) O[nt][r] *= scl[r];
    #pragma unroll
    for (int ks = 0; ks < 4; ++ks) {
      bf16x8 pf = *(const bf16x8*)&P_lds[wid][l16 * VTS_ + ks * 32 + lq * 8];
      #pragma unroll
      for (int nt = 0; nt < 5; ++nt) {
        bf16x8 vf = *(const bf16x8*)&Vt_lds[(nt * 16 + l16) * VTS_ + ks * 32 + lq * 8];
        O[nt] = __builtin_amdgcn_mfma_f32_16x16x32_bf16(pf, vf, O[nt], 0, 0, 0);
      }
    }
    __syncthreads();
    if (c < 6) {
      #pragma unroll
      for (int i = 0; i < 4; ++i) {
        if (sval[i]) {
          *(u16x8*)&K_lds[srow[i] * AKS_ + scol[i] * 8] = kreg[i];
          #pragma unroll
          for (int e = 0; e < 8; ++e)
            Vt_lds[(scol[i] * 8 + e) * VTS_ + srow[i]] = vreg[i][e];
        }
      }
      __syncthreads();
    }
  }
  float inv[4];
  #pragma unroll
  for (int r = 0; r < 4; ++r) inv[r] = 1.f / l_r[r];
  #pragma unroll
  for (int nt = 0; nt < 5; ++nt) {
    int d = nt * 16 + l16;
    if (d >= HD_) continue;
    #pragma unroll
    for (int r = 0; r < 4; ++r) {
      int a = wid * 16 + lq * 4 + r;
      if (a < AGENT_)
        agent_v[(((size_t)b * HEADS_ + h) * AGENT_ + a) * HD_ + d] = O[nt][r] * inv[r];
    }
  }
}

// ---------------- q attention ----------------
__global__ __launch_bounds__(256) void q_attn_kernel(
    const ushort_t* __restrict__ qkvb, const float* __restrict__ agent,
    const float* __restrict__ agent_v, const float* __restrict__ qbias,
    float* __restrict__ xf) {
  __shared__ float ag_t[HD_ * 52];
  __shared__ float av_t[HD_ * 52];
  const int tid = threadIdx.x;
  const int h = blockIdx.y, b = blockIdx.z;
  for (int t = tid; t < AGENT_ * HD_; t += 256) {
    int a = t / HD_, d = t % HD_;
    ag_t[d * 52 + a] = agent[((size_t)b * AGENT_ + a) * C_ + h * HD_ + d];
    av_t[d * 52 + a] = agent_v[(((size_t)b * HEADS_ + h) * AGENT_ + a) * HD_ + d];
  }
  __syncthreads();
  const int n = blockIdx.x * 256 + tid;
  if (n >= N_) return;
  const ushort_t* qp = qkvb + ((size_t)b * N_ + n) * QKVW_ + h * HD_;
  const float* qb = qbias + ((size_t)h * N_ + n) * AGENT_;
  float lg[AGENT_];
  #pragma unroll
  for (int a = 0; a < AGENT_; ++a) lg[a] = qb[a];
  for (int d = 0; d < HD_; ++d) {
    float qd = bf2f(qp[d]) * SCALE_;
    #pragma unroll
    for (int a = 0; a < AGENT_; ++a) lg[a] += qd * ag_t[d * 52 + a];
  }
  float mx = -1e30f;
  #pragma unroll
  for (int a = 0; a < AGENT_; ++a) mx = fmaxf(mx, lg[a]);
  float s = 0.f;
  #pragma unroll
  for (int a = 0; a < AGENT_; ++a) { lg[a] = __expf(lg[a] - mx); s += lg[a]; }
  float inv = 1.f / s;
  #pragma unroll
  for (int a = 0; a < AGENT_; ++a) lg[a] *= inv;
  float* op = xf + ((size_t)b * N_ + n) * C_ + h * HD_;
  for (int d = 0; d < HD_; ++d) {
    float acc = 0.f;
    #pragma unroll
    for (int a = 0; a < AGENT_; ++a) acc += lg[a] * av_t[d * 52 + a];
    op[d] = acc;
  }
}

// ---------------- depthwise conv + BN + ReLU (2ch/thread, XCD swizzle) ------
__global__ __launch_bounds__(288) void dwc_kernel(
    const ushort_t* __restrict__ qkvb, const float* __restrict__ w,
    const float* __restrict__ bias, const float* __restrict__ gamma,
    const float* __restrict__ beta, const float* __restrict__ mean,
    const float* __restrict__ var, float* __restrict__ xf) {
  int lin = blockIdx.x;
  const int bn = (lin & 7) * 3136 + (lin >> 3);   // 25088 = 8*3136, bijective
  const int b = bn / N_, n = bn % N_;
  const int y = n / W_, x = n % W_;
  const int c0 = threadIdx.x * 2;
  float a0 = 0.f, a1 = 0.f;
  #pragma unroll
  for (int ky = 0; ky < 3; ++ky) {
    int yy = y + ky - 1;
    if (yy < 0 || yy >= H_) continue;
    #pragma unroll
    for (int kx = 0; kx < 3; ++kx) {
      int xx = x + kx - 1;
      if (xx < 0 || xx >= W_) continue;
      unsigned v = *(const unsigned*)(qkvb + ((size_t)b * N_ + yy * W_ + xx) * QKVW_ + 2 * C_ + c0);
      a0 += w[c0 * 9 + ky * 3 + kx] * bf2f((ushort_t)(v & 0xffffu));
      a1 += w[(c0 + 1) * 9 + ky * 3 + kx] * bf2f((ushort_t)(v >> 16));
    }
  }
  float s0 = gamma[c0] * rsqrtf(var[c0] + 1e-5f);
  float s1 = gamma[c0 + 1] * rsqrtf(var[c0 + 1] + 1e-5f);
  float r0 = fmaxf((a0 + bias[c0] - mean[c0]) * s0 + beta[c0], 0.f);
  float r1 = fmaxf((a1 + bias[c0 + 1] - mean[c0 + 1]) * s1 + beta[c0 + 1], 0.f);
  float2* xp = (float2*)&xf[(size_t)bn * C_ + c0];
  float2 old = *xp;
  old.x += r0; old.y += r1;
  *xp = old;
}

extern "C" void kernel_launch(void* const* d_in, const int* in_sizes, int n_in,
                              void* d_out, int out_size, void* d_ws, size_t ws_size,
                              hipStream_t stream) {
  const float* x        = (const float*)d_in[0];
  const float* Wq       = (const float*)d_in[3];
  const float* Wkv      = (const float*)d_in[4];
  const float* an_bias  = (const float*)d_in[5];
  const float* na_bias  = (const float*)d_in[6];
  const float* ah_bias  = (const float*)d_in[7];
  const float* aw_bias  = (const float*)d_in[8];
  const float* ha_bias  = (const float*)d_in[9];
  const float* wa_bias  = (const float*)d_in[10];
  const float* dwc_w    = (const float*)d_in[11];
  const float* dwc_b    = (const float*)d_in[12];
  const float* bn_gamma = (const float*)d_in[13];
  const float* bn_beta  = (const float*)d_in[14];
  const float* bn_mean  = (const float*)d_in[15];
  const float* bn_var   = (const float*)d_in[16];
  const float* base_w   = (const float*)d_in[17];
  const float* spline_w = (const float*)d_in[18];
  const float* spline_s = (const float*)d_in[19];

  char* ws = (char*)d_ws;
  ushort_t* qkvb   = (ushort_t*)(ws + 0);
  ushort_t* xbf    = (ushort_t*)(ws + 86704128);
  ushort_t* wbf    = (ushort_t*)(ws + 115605504);
  ushort_t* bpackb = (ushort_t*)(ws + 117596160);
  float* agent     = (float*)(ws + 123568128);
  float* agent_v   = (float*)(ws + 127180800);
  float* abias     = (float*)(ws + 130793472);
  float* qbias     = (float*)(ws + 132022784);
  float* xf        = (float*)(ws + 133252096);
  float* out       = (float*)d_out;

  convert_x_kernel<<<dim3(2048), dim3(256), 0, stream>>>(x, xbf);
  pack_w_kernel<<<dim3(1024), dim3(256), 0, stream>>>(Wq, Wkv, wbf);
  pack_b_kernel<<<dim3(C_), dim3(256), 0, stream>>>(base_w, spline_w, spline_s, bpackb);
  bias_kernel<<<dim3((HEADS_ * AGENT_ * N_ + 255) / 256), dim3(256), 0, stream>>>(
      an_bias, na_bias, ah_bias, aw_bias, ha_bias, wa_bias, abias, qbias);
  mfma_qkv_kernel<<<dim3(1764), dim3(512), 0, stream>>>(xbf, wbf, qkvb);
  agent_pool_kernel<<<dim3(B_ * AGENT_), dim3(C_), 0, stream>>>(qkvb, agent);
  agent_attn_mfma_kernel<<<dim3(B_ * HEADS_), dim3(256), 0, stream>>>(
      agent, qkvb, abias, agent_v);
  q_attn_kernel<<<dim3(4, HEADS_, B_), dim3(256), 0, stream>>>(
      qkvb, agent, agent_v, qbias, xf);
  dwc_kernel<<<dim3(M_), dim3(288), 0, stream>>>(
      qkvb, dwc_w, dwc_b, bn_gamma, bn_beta, bn_mean, bn_var, xf);
  kan_mfma_kernel<<<dim3(588), dim3(512), 0, stream>>>(xf, bpackb, out);
}

// Round 11
// 618.176 us; speedup vs baseline: 1.1044x; 1.0200x over previous
//
#include <hip/hip_runtime.h>
#include <hip/hip_bf16.h>
#include <math.h>

#define B_ 32
#define N_ 784
#define C_ 576
#define H_ 28
#define W_ 28
#define HEADS_ 8
#define HD_ 72
#define AGENT_ 49
#define M_ (B_ * N_)            // 25088
#define KTOT_ 5184              // 576 silu + 576*8 spline
#define QKVW_ 1728
#define SCALE_ 0.11785113019775793f

// BK=64 swizzled LDS: row stride 64 elems (128 B); 16B chunks XOR'd by row&7.
#define SWZ64(row, chunk) (((row) << 6) + ((((chunk) ^ ((row) & 7))) << 3))

typedef unsigned short ushort_t;
typedef __attribute__((ext_vector_type(8))) unsigned short u16x8;
typedef __attribute__((ext_vector_type(8))) __bf16 bf16x8;
typedef __attribute__((ext_vector_type(4))) float f32x4;
typedef __attribute__((ext_vector_type(4))) unsigned u32x4;

__device__ __forceinline__ ushort_t f2bf(float f) {
  union { float f; unsigned u; } v; v.f = f;
  unsigned r = v.u + 0x7fffu + ((v.u >> 16) & 1u);
  return (ushort_t)(r >> 16);
}
__device__ __forceinline__ float bf2f(ushort_t u) {
  union { unsigned u; float f; } v; v.u = ((unsigned)u) << 16;
  return v.f;
}
__device__ __forceinline__ unsigned pack2(float lo, float hi) {
  __bf16 a = (__bf16)lo, b = (__bf16)hi;
  unsigned short ua = __builtin_bit_cast(unsigned short, a);
  unsigned short ub = __builtin_bit_cast(unsigned short, b);
  return (unsigned)ua | ((unsigned)ub << 16);
}

// ---------------- converts / packs ----------------
__global__ __launch_bounds__(256) void convert_x_kernel(
    const float* __restrict__ x, ushort_t* __restrict__ xbf) {
  const int total8 = M_ * C_ / 8;
  for (int i = blockIdx.x * 256 + threadIdx.x; i < total8; i += gridDim.x * 256) {
    f32x4 a = *(const f32x4*)(x + i * 8);
    f32x4 b = *(const f32x4*)(x + i * 8 + 4);
    u16x8 o;
    o[0]=f2bf(a[0]); o[1]=f2bf(a[1]); o[2]=f2bf(a[2]); o[3]=f2bf(a[3]);
    o[4]=f2bf(b[0]); o[5]=f2bf(b[1]); o[6]=f2bf(b[2]); o[7]=f2bf(b[3]);
    *(u16x8*)(xbf + i * 8) = o;
  }
}

__global__ __launch_bounds__(256) void pack_w_kernel(
    const float* __restrict__ Wq, const float* __restrict__ Wkv,
    ushort_t* __restrict__ wbf) {
  int total = QKVW_ * C_;
  for (int i = blockIdx.x * 256 + threadIdx.x; i < total; i += gridDim.x * 256) {
    int j = i / C_, k = i % C_;
    float v = (j < C_) ? Wq[(size_t)j * C_ + k] : Wkv[(size_t)(j - C_) * C_ + k];
    wbf[i] = f2bf(v);
  }
}

__global__ __launch_bounds__(256) void pack_b_kernel(
    const float* __restrict__ base_w, const float* __restrict__ spline_w,
    const float* __restrict__ spline_s, ushort_t* __restrict__ bpackb) {
  int o = blockIdx.x;
  for (int j = threadIdx.x; j < KTOT_; j += 256) {
    float v;
    if (j < C_) {
      v = base_w[(size_t)o * C_ + j];
    } else {
      int jj = j - C_;
      int i = jj >> 3, kk = jj & 7;
      v = spline_w[((size_t)o * C_ + i) * 8 + kk] * spline_s[(size_t)o * C_ + i];
    }
    bpackb[(size_t)o * KTOT_ + j] = f2bf(v);
  }
}

// ---------------- bias precompute ----------------
__device__ __forceinline__ float bilerp7(const float* __restrict__ Bsrc, int y, int x) {
  float sy = y * 0.25f - 0.375f;
  float sx = x * 0.25f - 0.375f;
  float fy0 = floorf(sy), fx0 = floorf(sx);
  int y0 = (int)fy0, x0 = (int)fx0;
  float fy = sy - fy0, fx = sx - fx0;
  int y0c = min(6, max(0, y0)), y1c = min(6, max(0, y0 + 1));
  int x0c = min(6, max(0, x0)), x1c = min(6, max(0, x0 + 1));
  float v00 = Bsrc[y0c * 7 + x0c], v01 = Bsrc[y0c * 7 + x1c];
  float v10 = Bsrc[y1c * 7 + x0c], v11 = Bsrc[y1c * 7 + x1c];
  return (1.f - fy) * ((1.f - fx) * v00 + fx * v01)
       + fy * ((1.f - fx) * v10 + fx * v11);
}

__global__ __launch_bounds__(256) void bias_kernel(
    const float* __restrict__ an_bias, const float* __restrict__ na_bias,
    const float* __restrict__ ah_bias, const float* __restrict__ aw_bias,
    const float* __restrict__ ha_bias, const float* __restrict__ wa_bias,
    float* __restrict__ abias, float* __restrict__ qbias) {
  int idx = blockIdx.x * 256 + threadIdx.x;
  if (idx >= HEADS_ * AGENT_ * N_) return;
  int n = idx % N_;
  int ha = idx / N_;
  int h = ha / AGENT_, a = ha % AGENT_;
  int y = n / W_, x = n % W_;
  float pb1 = bilerp7(an_bias + (size_t)ha * 49, y, x);
  float pb2 = ah_bias[ha * H_ + y] + aw_bias[ha * W_ + x];
  abias[(size_t)ha * N_ + n] = pb1 + pb2;
  float ab1 = bilerp7(na_bias + (size_t)ha * 49, y, x);
  float ab2 = ha_bias[(h * H_ + y) * AGENT_ + a] + wa_bias[(h * W_ + x) * AGENT_ + a];
  qbias[((size_t)h * N_ + n) * AGENT_ + a] = ab1 + ab2;
}

// ---------------- MFMA GEMM: qkv (8 waves, BK=64, write/load-first order) ---
// grid: 1764 = 196 row-tiles x 9 col-tiles (col fastest); 1764 = 8*220+4
__global__ __launch_bounds__(512, 4) void mfma_qkv_kernel(
    const ushort_t* __restrict__ A, const ushort_t* __restrict__ Bt,
    ushort_t* __restrict__ out) {
  __shared__ ushort_t Asl[2][128 * 64];   // 32 KB
  __shared__ ushort_t Bsl[2][192 * 64];   // 48 KB
  const int tid = threadIdx.x;
  const int lane = tid & 63, wid = tid >> 6;
  const int wm = wid >> 2, wn = wid & 3;
  const int l16 = lane & 15, lq = lane >> 4;

  int lin = blockIdx.x;
  const int q = 220, r = 4;          // 1764 = 8*220+4
  int xcd = lin & 7;
  int wg = (xcd < r ? xcd * (q + 1) : r * (q + 1) + (xcd - r) * q) + (lin >> 3);
  const int m0 = (wg / 9) * 128, n0 = (wg % 9) * 192;

  const int srowi = tid >> 3;        // 0..63
  const int chk = tid & 7;           // 0..7

  const ushort_t* arow0 = A + (size_t)(m0 + srowi) * C_ + chk * 8;
  const ushort_t* arow1 = arow0 + (size_t)64 * C_;
  const ushort_t* brow0 = Bt + (size_t)(n0 + srowi) * C_ + chk * 8;
  const ushort_t* brow1 = brow0 + (size_t)64 * C_;
  const ushort_t* brow2 = brow0 + (size_t)128 * C_;

  const int aW0 = SWZ64(srowi, chk), aW1 = SWZ64(srowi + 64, chk);
  const int bW0 = SWZ64(srowi, chk), bW1 = SWZ64(srowi + 64, chk),
            bW2 = SWZ64(srowi + 128, chk);

  f32x4 acc[4][3] = {};
  u16x8 ar0, ar1, br0, br1, br2;

  // prologue: step0 load + write buf0, step1 load
  ar0 = *(const u16x8*)(arow0);
  ar1 = *(const u16x8*)(arow1);
  br0 = *(const u16x8*)(brow0);
  br1 = *(const u16x8*)(brow1);
  br2 = *(const u16x8*)(brow2);
  *(u16x8*)&Asl[0][aW0] = ar0;
  *(u16x8*)&Asl[0][aW1] = ar1;
  *(u16x8*)&Bsl[0][bW0] = br0;
  *(u16x8*)&Bsl[0][bW1] = br1;
  *(u16x8*)&Bsl[0][bW2] = br2;
  ar0 = *(const u16x8*)(arow0 + 64);
  ar1 = *(const u16x8*)(arow1 + 64);
  br0 = *(const u16x8*)(brow0 + 64);
  br1 = *(const u16x8*)(brow1 + 64);
  br2 = *(const u16x8*)(brow2 + 64);
  __syncthreads();

  const int NSTEP = C_ / 64;   // 9
  for (int s = 0; s < NSTEP; ++s) {
    const int cur = s & 1;
    // 1) write nxt buffer with regs for step s+1 (issue-early/write-late: T14)
    if (s + 1 < NSTEP) {
      const int nxt = cur ^ 1;
      *(u16x8*)&Asl[nxt][aW0] = ar0;
      *(u16x8*)&Asl[nxt][aW1] = ar1;
      *(u16x8*)&Bsl[nxt][bW0] = br0;
      *(u16x8*)&Bsl[nxt][bW1] = br1;
      *(u16x8*)&Bsl[nxt][bW2] = br2;
      // 2) issue global loads for step s+2 — land during MFMA below
      if (s + 2 < NSTEP) {
        const int kl = (s + 2) * 64;
        ar0 = *(const u16x8*)(arow0 + kl);
        ar1 = *(const u16x8*)(arow1 + kl);
        br0 = *(const u16x8*)(brow0 + kl);
        br1 = *(const u16x8*)(brow1 + kl);
        br2 = *(const u16x8*)(brow2 + kl);
      }
    }
    // 3) MFMA on cur
    #pragma unroll
    for (int ks = 0; ks < 2; ++ks) {
      bf16x8 af[4], bfr[3];
      #pragma unroll
      for (int fm = 0; fm < 4; ++fm)
        af[fm] = *(const bf16x8*)&Asl[cur][SWZ64(wm * 64 + fm * 16 + l16, ks * 4 + lq)];
      #pragma unroll
      for (int fn = 0; fn < 3; ++fn)
        bfr[fn] = *(const bf16x8*)&Bsl[cur][SWZ64(wn * 48 + fn * 16 + l16, ks * 4 + lq)];
      #pragma unroll
      for (int fm = 0; fm < 4; ++fm)
        #pragma unroll
        for (int fn = 0; fn < 3; ++fn)
          acc[fm][fn] = __builtin_amdgcn_mfma_f32_16x16x32_bf16(
              af[fm], bfr[fn], acc[fm][fn], 0, 0, 0);
    }
    __syncthreads();
  }
  #pragma unroll
  for (int fm = 0; fm < 4; ++fm) {
    #pragma unroll
    for (int fn = 0; fn < 3; ++fn) {
      int col = n0 + wn * 48 + fn * 16 + l16;
      #pragma unroll
      for (int r2 = 0; r2 < 4; ++r2) {
        int row = m0 + wm * 64 + fm * 16 + lq * 4 + r2;
        out[(size_t)row * QKVW_ + col] = f2bf(acc[fm][fn][r2]);
      }
    }
  }
}

// ---------------- KAN A-operand generation (funnel-shift placement) --------
__device__ __forceinline__ u32x4 basesPack(float xv) {
  float s = __fmaf_rn(xv, 2.5f, 5.5f);
  float tf = floorf(s);
  int t = (int)tf;
  float u = s - tf;
  float u2 = u * u, u3 = u2 * u, um = 1.f - u;
  float p0 = u3 * (1.f / 6.f);
  float p1 = __fmaf_rn(u3, -0.5f, __fmaf_rn(u2, 0.5f, __fmaf_rn(u, 0.5f, 1.f / 6.f)));
  float p2 = __fmaf_rn(u3, 0.5f, __fmaf_rn(u2, -1.f, 2.f / 3.f));
  float p3 = um * um * um * (1.f / 6.f);
  unsigned lo = pack2(p3, p2);          // slot0=p3, slot1=p2
  unsigned hi = pack2(p1, p0);          // slot2=p1, slot3=p0
  unsigned long long packed = ((unsigned long long)hi << 32) | (unsigned long long)lo;
  int sh = t - 3;
  int ba = sh << 4;
  unsigned long long shl_lo = packed << (ba & 63);
  unsigned long long shr_sp = packed >> ((64 - ba) & 63);
  unsigned long long shl_hi = packed << ((ba - 64) & 63);
  unsigned long long shr_ng = packed >> ((-ba) & 63);
  unsigned long long Olo = (sh < 0) ? shr_ng : ((sh < 4) ? shl_lo : 0ull);
  unsigned long long Ohi = (sh <= 0) ? 0ull : ((sh < 4) ? shr_sp : shl_hi);
  if (t < 0 || t > 10) { Olo = 0ull; Ohi = 0ull; }
  u32x4 o;
  o[0] = (unsigned)Olo; o[1] = (unsigned)(Olo >> 32);
  o[2] = (unsigned)Ohi; o[3] = (unsigned)(Ohi >> 32);
  return o;
}

__device__ __forceinline__ u32x4 siluPack(const float* xv) {
  u32x4 o;
  #pragma unroll
  for (int e = 0; e < 4; ++e) {
    float v0 = xv[2 * e], v1 = xv[2 * e + 1];
    float s0 = v0 / (1.f + __expf(-v0));
    float s1 = v1 / (1.f + __expf(-v1));
    o[e] = pack2(s0, s1);
  }
  return o;
}

// ---------------- KAN MFMA GEMM (8 waves, BK=64, write/load-first order) ----
// grid: 588 = 196 row-tiles x 3 col-tiles (col fastest); 588 = 8*73+4
__global__ __launch_bounds__(512, 4) void kan_mfma_kernel(
    const float* __restrict__ xf, const ushort_t* __restrict__ Bt,
    float* __restrict__ out) {
  __shared__ ushort_t Asl[2][128 * 64];   // 32 KB
  __shared__ ushort_t Bsl[2][192 * 64];   // 48 KB
  const int tid = threadIdx.x;
  const int lane = tid & 63, wid = tid >> 6;
  const int wm = wid >> 2, wn = wid & 3;
  const int l16 = lane & 15, lq = lane >> 4;

  int lin = blockIdx.x;
  const int q = 73, r = 4;           // 588 = 8*73+4
  int xcd = lin & 7;
  int wg = (xcd < r ? xcd * (q + 1) : r * (q + 1) + (xcd - r) * q) + (lin >> 3);
  const int m0 = (wg / 3) * 128, n0 = (wg % 3) * 192;

  const int srowi = tid >> 3;        // 0..63
  const int chk = tid & 7;           // 0..7

  const float* xfr0 = xf + (size_t)(m0 + srowi) * C_;
  const float* xfr1 = xfr0 + (size_t)64 * C_;
  const ushort_t* brow0 = Bt + (size_t)(n0 + srowi) * KTOT_ + chk * 8;
  const ushort_t* brow1 = brow0 + (size_t)64 * KTOT_;
  const ushort_t* brow2 = brow0 + (size_t)128 * KTOT_;

  const int aW0 = SWZ64(srowi, chk), aW1 = SWZ64(srowi + 64, chk);
  const int bW0 = SWZ64(srowi, chk), bW1 = SWZ64(srowi + 64, chk),
            bW2 = SWZ64(srowi + 128, chk);

  f32x4 acc[4][3] = {};
  float xv0[8], xv1[8];
  u16x8 br0, br1, br2;

  // prologue: step0 load + gen + write buf0, step1 load
  {
    f32x4 a = *(const f32x4*)(xfr0 + chk * 8);
    f32x4 b = *(const f32x4*)(xfr0 + chk * 8 + 4);
    xv0[0]=a[0]; xv0[1]=a[1]; xv0[2]=a[2]; xv0[3]=a[3];
    xv0[4]=b[0]; xv0[5]=b[1]; xv0[6]=b[2]; xv0[7]=b[3];
    f32x4 c = *(const f32x4*)(xfr1 + chk * 8);
    f32x4 d = *(const f32x4*)(xfr1 + chk * 8 + 4);
    xv1[0]=c[0]; xv1[1]=c[1]; xv1[2]=c[2]; xv1[3]=c[3];
    xv1[4]=d[0]; xv1[5]=d[1]; xv1[6]=d[2]; xv1[7]=d[3];
  }
  br0 = *(const u16x8*)(brow0);
  br1 = *(const u16x8*)(brow1);
  br2 = *(const u16x8*)(brow2);
  *(u32x4*)&Asl[0][aW0] = siluPack(xv0);
  *(u32x4*)&Asl[0][aW1] = siluPack(xv1);
  *(u16x8*)&Bsl[0][bW0] = br0;
  *(u16x8*)&Bsl[0][bW1] = br1;
  *(u16x8*)&Bsl[0][bW2] = br2;
  {
    f32x4 a = *(const f32x4*)(xfr0 + 64 + chk * 8);
    f32x4 b = *(const f32x4*)(xfr0 + 64 + chk * 8 + 4);
    xv0[0]=a[0]; xv0[1]=a[1]; xv0[2]=a[2]; xv0[3]=a[3];
    xv0[4]=b[0]; xv0[5]=b[1]; xv0[6]=b[2]; xv0[7]=b[3];
    f32x4 c = *(const f32x4*)(xfr1 + 64 + chk * 8);
    f32x4 d = *(const f32x4*)(xfr1 + 64 + chk * 8 + 4);
    xv1[0]=c[0]; xv1[1]=c[1]; xv1[2]=c[2]; xv1[3]=c[3];
    xv1[4]=d[0]; xv1[5]=d[1]; xv1[6]=d[2]; xv1[7]=d[3];
  }
  br0 = *(const u16x8*)(brow0 + 64);
  br1 = *(const u16x8*)(brow1 + 64);
  br2 = *(const u16x8*)(brow2 + 64);
  __syncthreads();

  const int NSTEP = KTOT_ / 64;   // 81
  for (int s = 0; s < NSTEP; ++s) {
    const int cur = s & 1;
    // 1) gen A(s+1) + write nxt; 2) issue loads for s+2 (hidden under MFMA)
    if (s + 1 < NSTEP) {
      const int nxt = cur ^ 1;
      const int kg = (s + 1) * 64;
      u32x4 a0, a1;
      if (kg < C_) { a0 = siluPack(xv0); a1 = siluPack(xv1); }
      else         { a0 = basesPack(xv0[0]); a1 = basesPack(xv1[0]); }
      *(u32x4*)&Asl[nxt][aW0] = a0;
      *(u32x4*)&Asl[nxt][aW1] = a1;
      *(u16x8*)&Bsl[nxt][bW0] = br0;
      *(u16x8*)&Bsl[nxt][bW1] = br1;
      *(u16x8*)&Bsl[nxt][bW2] = br2;
      if (s + 2 < NSTEP) {
        const int kl = (s + 2) * 64;
        if (kl < C_) {
          f32x4 a = *(const f32x4*)(xfr0 + kl + chk * 8);
          f32x4 b = *(const f32x4*)(xfr0 + kl + chk * 8 + 4);
          xv0[0]=a[0]; xv0[1]=a[1]; xv0[2]=a[2]; xv0[3]=a[3];
          xv0[4]=b[0]; xv0[5]=b[1]; xv0[6]=b[2]; xv0[7]=b[3];
          f32x4 c = *(const f32x4*)(xfr1 + kl + chk * 8);
          f32x4 d = *(const f32x4*)(xfr1 + kl + chk * 8 + 4);
          xv1[0]=c[0]; xv1[1]=c[1]; xv1[2]=c[2]; xv1[3]=c[3];
          xv1[4]=d[0]; xv1[5]=d[1]; xv1[6]=d[2]; xv1[7]=d[3];
        } else {
          int i0 = ((kl - C_) >> 3) + chk;
          xv0[0] = xfr0[i0];
          xv1[0] = xfr1[i0];
        }
        br0 = *(const u16x8*)(brow0 + kl);
        br1 = *(const u16x8*)(brow1 + kl);
        br2 = *(const u16x8*)(brow2 + kl);
      }
    }
    // 3) MFMA on cur
    #pragma unroll
    for (int ks = 0; ks < 2; ++ks) {
      bf16x8 af[4], bfr[3];
      #pragma unroll
      for (int fm = 0; fm < 4; ++fm)
        af[fm] = *(const bf16x8*)&Asl[cur][SWZ64(wm * 64 + fm * 16 + l16, ks * 4 + lq)];
      #pragma unroll
      for (int fn = 0; fn < 3; ++fn)
        bfr[fn] = *(const bf16x8*)&Bsl[cur][SWZ64(wn * 48 + fn * 16 + l16, ks * 4 + lq)];
      #pragma unroll
      for (int fm = 0; fm < 4; ++fm)
        #pragma unroll
        for (int fn = 0; fn < 3; ++fn)
          acc[fm][fn] = __builtin_amdgcn_mfma_f32_16x16x32_bf16(
              af[fm], bfr[fn], acc[fm][fn], 0, 0, 0);
    }
    __syncthreads();
  }
  #pragma unroll
  for (int fm = 0; fm < 4; ++fm) {
    #pragma unroll
    for (int fn = 0; fn < 3; ++fn) {
      int col = n0 + wn * 48 + fn * 16 + l16;
      #pragma unroll
      for (int r2 = 0; r2 < 4; ++r2) {
        int row = m0 + wm * 64 + fm * 16 + lq * 4 + r2;
        out[(size_t)row * C_ + col] = acc[fm][fn][r2];
      }
    }
  }
}

// ---------------- agent pooling ----------------
__global__ __launch_bounds__(576) void agent_pool_kernel(
    const ushort_t* __restrict__ qkvb, float* __restrict__ agent) {
  int ba = blockIdx.x;
  int b = ba / AGENT_, a = ba % AGENT_;
  int ay = a / 7, ax = a % 7;
  int ch = threadIdx.x;
  float s = 0.f;
  #pragma unroll
  for (int i2 = 0; i2 < 4; ++i2)
    #pragma unroll
    for (int i4 = 0; i4 < 4; ++i4)
      s += bf2f(qkvb[((size_t)b * N_ + (ay * 4 + i2) * W_ + (ax * 4 + i4)) * QKVW_ + ch]);
  agent[(size_t)ba * C_ + ch] = s * 0.0625f;
}

// ---------------- agent attention v3: MFMA flash, one block per (b,h) -------
#define AKS_ 104
#define VTS_ 136
__global__ __launch_bounds__(256) void agent_attn_mfma_kernel(
    const float* __restrict__ agent, const ushort_t* __restrict__ qkvb,
    const float* __restrict__ abias, float* __restrict__ agent_v) {
  __shared__ ushort_t A_lds[64 * AKS_];
  __shared__ ushort_t K_lds[112 * AKS_];
  __shared__ ushort_t Vt_lds[80 * VTS_];
  __shared__ ushort_t P_lds[4][16 * VTS_];
  const int tid = threadIdx.x;
  const int lane = tid & 63, wid = tid >> 6;
  const int l16 = lane & 15, lq = lane >> 4;
  const int b = blockIdx.x >> 3, h = blockIdx.x & 7;

  for (int i = tid; i < 64 * AKS_; i += 256) A_lds[i] = 0;
  for (int i = tid; i < 112 * 32; i += 256) {
    int r = i >> 5, cc = 72 + (i & 31);
    K_lds[r * AKS_ + cc] = 0;
  }
  for (int i = tid; i < 80 * VTS_; i += 256) Vt_lds[i] = 0;
  for (int i = tid; i < 4 * 16 * 24; i += 256) {
    int w = i / (16 * 24), rest = i % (16 * 24);
    int r = rest / 24, cc = 112 + rest % 24;
    P_lds[w][r * VTS_ + cc] = 0;
  }
  for (int i = tid; i < AGENT_ * HD_; i += 256) {
    int a = i / HD_, d = i % HD_;
    A_lds[a * AKS_ + d] = f2bf(agent[((size_t)b * AGENT_ + a) * C_ + h * HD_ + d]);
  }

  int srow[4], scol[4]; bool sval[4];
  #pragma unroll
  for (int i = 0; i < 4; ++i) {
    int idx = tid + i * 256;
    srow[i] = idx / 9; scol[i] = idx % 9;
    sval[i] = idx < 1008;
  }
  const ushort_t* kbase = qkvb + (size_t)b * N_ * QKVW_ + C_ + h * HD_;
  const ushort_t* vbase = qkvb + (size_t)b * N_ * QKVW_ + 2 * C_ + h * HD_;

  u16x8 kreg[4], vreg[4];
  #pragma unroll
  for (int i = 0; i < 4; ++i) {
    if (sval[i]) {
      kreg[i] = *(const u16x8*)(kbase + (size_t)srow[i] * QKVW_ + scol[i] * 8);
      vreg[i] = *(const u16x8*)(vbase + (size_t)srow[i] * QKVW_ + scol[i] * 8);
    }
  }
  #pragma unroll
  for (int i = 0; i < 4; ++i) {
    if (sval[i]) {
      *(u16x8*)&K_lds[srow[i] * AKS_ + scol[i] * 8] = kreg[i];
      #pragma unroll
      for (int e = 0; e < 8; ++e)
        Vt_lds[(scol[i] * 8 + e) * VTS_ + srow[i]] = vreg[i][e];
    }
  }
  __syncthreads();

  float m_r[4] = {-1e30f, -1e30f, -1e30f, -1e30f};
  float l_r[4] = {};
  f32x4 O[5] = {};
  const float* bias_base[4];
  #pragma unroll
  for (int r = 0; r < 4; ++r) {
    int a = wid * 16 + lq * 4 + r;
    a = min(a, AGENT_ - 1);
    bias_base[r] = abias + ((size_t)h * AGENT_ + a) * N_;
  }

  for (int c = 0; c < 7; ++c) {
    if (c < 6) {
      const size_t off = (size_t)(c + 1) * 112 * QKVW_;
      #pragma unroll
      for (int i = 0; i < 4; ++i) {
        if (sval[i]) {
          kreg[i] = *(const u16x8*)(kbase + off + (size_t)srow[i] * QKVW_ + scol[i] * 8);
          vreg[i] = *(const u16x8*)(vbase + off + (size_t)srow[i] * QKVW_ + scol[i] * 8);
        }
      }
    }
    f32x4 sacc[7] = {};
    #pragma unroll
    for (int ks = 0; ks < 3; ++ks) {
      bf16x8 af = *(const bf16x8*)&A_lds[(wid * 16 + l16) * AKS_ + ks * 32 + lq * 8];
      #pragma unroll
      for (int nt = 0; nt < 7; ++nt) {
        bf16x8 bf = *(const bf16x8*)&K_lds[(nt * 16 + l16) * AKS_ + ks * 32 + lq * 8];
        sacc[nt] = __builtin_amdgcn_mfma_f32_16x16x32_bf16(af, bf, sacc[nt], 0, 0, 0);
      }
    }
    float cmax[4] = {-1e30f, -1e30f, -1e30f, -1e30f};
    const int nb = c * 112 + l16;
    #pragma unroll
    for (int nt = 0; nt < 7; ++nt)
      #pragma unroll
      for (int r = 0; r < 4; ++r) {
        float lg = sacc[nt][r] * SCALE_ + bias_base[r][nb + nt * 16];
        sacc[nt][r] = lg;
        cmax[r] = fmaxf(cmax[r], lg);
      }
    #pragma unroll
    for (int off = 1; off < 16; off <<= 1)
      #pragma unroll
      for (int r = 0; r < 4; ++r)
        cmax[r] = fmaxf(cmax[r], __shfl_xor(cmax[r], off));
    float scl[4], rs[4];
    #pragma unroll
    for (int r = 0; r < 4; ++r) {
      float nm = fmaxf(m_r[r], cmax[r]);
      scl[r] = __expf(m_r[r] - nm);
      m_r[r] = nm;
      rs[r] = 0.f;
    }
    #pragma unroll
    for (int nt = 0; nt < 7; ++nt)
      #pragma unroll
      for (int r = 0; r < 4; ++r) {
        float p = __expf(sacc[nt][r] - m_r[r]);
        rs[r] += p;
        P_lds[wid][(lq * 4 + r) * VTS_ + nt * 16 + l16] = f2bf(p);
      }
    #pragma unroll
    for (int off = 1; off < 16; off <<= 1)
      #pragma unroll
      for (int r = 0; r < 4; ++r)
        rs[r] += __shfl_xor(rs[r], off);
    #pragma unroll
    for (int r = 0; r < 4; ++r) l_r[r] = l_r[r] * scl[r] + rs[r];
    #pragma unroll
    for (int nt = 0; nt < 5; ++nt)
      #pragma unroll
      for (int r = 0; r < 4; ++r) O[nt][r] *= scl[r];
    #pragma unroll
    for (int ks = 0; ks < 4; ++ks) {
      bf16x8 pf = *(const bf16x8*)&P_lds[wid][l16 * VTS_ + ks * 32 + lq * 8];
      #pragma unroll
      for (int nt = 0; nt < 5; ++nt) {
        bf16x8 vf = *(const bf16x8*)&Vt_lds[(nt * 16 + l16) * VTS_ + ks * 32 + lq * 8];
        O[nt] = __builtin_amdgcn_mfma_f32_16x16x32_bf16(pf, vf, O[nt], 0, 0, 0);
      }
    }
    __syncthreads();
    if (c < 6) {
      #pragma unroll
      for (int i = 0; i < 4; ++i) {
        if (sval[i]) {
          *(u16x8*)&K_lds[srow[i] * AKS_ + scol[i] * 8] = kreg[i];
          #pragma unroll
          for (int e = 0; e < 8; ++e)
            Vt_lds[(scol[i] * 8 + e) * VTS_ + srow[i]] = vreg[i][e];
        }
      }
      __syncthreads();
    }
  }
  float inv[4];
  #pragma unroll
  for (int r = 0; r < 4; ++r) inv[r] = 1.f / l_r[r];
  #pragma unroll
  for (int nt = 0; nt < 5; ++nt) {
    int d = nt * 16 + l16;
    if (d >= HD_) continue;
    #pragma unroll
    for (int r = 0; r < 4; ++r) {
      int a = wid * 16 + lq * 4 + r;
      if (a < AGENT_)
        agent_v[(((size_t)b * HEADS_ + h) * AGENT_ + a) * HD_ + d] = O[nt][r] * inv[r];
    }
  }
}

// ---------------- q attention ----------------
__global__ __launch_bounds__(256) void q_attn_kernel(
    const ushort_t* __restrict__ qkvb, const float* __restrict__ agent,
    const float* __restrict__ agent_v, const float* __restrict__ qbias,
    float* __restrict__ xf) {
  __shared__ float ag_t[HD_ * 52];
  __shared__ float av_t[HD_ * 52];
  const int tid = threadIdx.x;
  const int h = blockIdx.y, b = blockIdx.z;
  for (int t = tid; t < AGENT_ * HD_; t += 256) {
    int a = t / HD_, d = t % HD_;
    ag_t[d * 52 + a] = agent[((size_t)b * AGENT_ + a) * C_ + h * HD_ + d];
    av_t[d * 52 + a] = agent_v[(((size_t)b * HEADS_ + h) * AGENT_ + a) * HD_ + d];
  }
  __syncthreads();
  const int n = blockIdx.x * 256 + tid;
  if (n >= N_) return;
  const ushort_t* qp = qkvb + ((size_t)b * N_ + n) * QKVW_ + h * HD_;
  const float* qb = qbias + ((size_t)h * N_ + n) * AGENT_;
  float lg[AGENT_];
  #pragma unroll
  for (int a = 0; a < AGENT_; ++a) lg[a] = qb[a];
  for (int d = 0; d < HD_; ++d) {
    float qd = bf2f(qp[d]) * SCALE_;
    #pragma unroll
    for (int a = 0; a < AGENT_; ++a) lg[a] += qd * ag_t[d * 52 + a];
  }
  float mx = -1e30f;
  #pragma unroll
  for (int a = 0; a < AGENT_; ++a) mx = fmaxf(mx, lg[a]);
  float s = 0.f;
  #pragma unroll
  for (int a = 0; a < AGENT_; ++a) { lg[a] = __expf(lg[a] - mx); s += lg[a]; }
  float inv = 1.f / s;
  #pragma unroll
  for (int a = 0; a < AGENT_; ++a) lg[a] *= inv;
  float* op = xf + ((size_t)b * N_ + n) * C_ + h * HD_;
  for (int d = 0; d < HD_; ++d) {
    float acc = 0.f;
    #pragma unroll
    for (int a = 0; a < AGENT_; ++a) acc += lg[a] * av_t[d * 52 + a];
    op[d] = acc;
  }
}

// ---------------- depthwise conv + BN + ReLU (2ch/thread, XCD swizzle) ------
__global__ __launch_bounds__(288) void dwc_kernel(
    const ushort_t* __restrict__ qkvb, const float* __restrict__ w,
    const float* __restrict__ bias, const float* __restrict__ gamma,
    const float* __restrict__ beta, const float* __restrict__ mean,
    const float* __restrict__ var, float* __restrict__ xf) {
  int lin = blockIdx.x;
  const int bn = (lin & 7) * 3136 + (lin >> 3);   // 25088 = 8*3136, bijective
  const int b = bn / N_, n = bn % N_;
  const int y = n / W_, x = n % W_;
  const int c0 = threadIdx.x * 2;
  float a0 = 0.f, a1 = 0.f;
  #pragma unroll
  for (int ky = 0; ky < 3; ++ky) {
    int yy = y + ky - 1;
    if (yy < 0 || yy >= H_) continue;
    #pragma unroll
    for (int kx = 0; kx < 3; ++kx) {
      int xx = x + kx - 1;
      if (xx < 0 || xx >= W_) continue;
      unsigned v = *(const unsigned*)(qkvb + ((size_t)b * N_ + yy * W_ + xx) * QKVW_ + 2 * C_ + c0);
      a0 += w[c0 * 9 + ky * 3 + kx] * bf2f((ushort_t)(v & 0xffffu));
      a1 += w[(c0 + 1) * 9 + ky * 3 + kx] * bf2f((ushort_t)(v >> 16));
    }
  }
  float s0 = gamma[c0] * rsqrtf(var[c0] + 1e-5f);
  float s1 = gamma[c0 + 1] * rsqrtf(var[c0 + 1] + 1e-5f);
  float r0 = fmaxf((a0 + bias[c0] - mean[c0]) * s0 + beta[c0], 0.f);
  float r1 = fmaxf((a1 + bias[c0 + 1] - mean[c0 + 1]) * s1 + beta[c0 + 1], 0.f);
  float2* xp = (float2*)&xf[(size_t)bn * C_ + c0];
  float2 old = *xp;
  old.x += r0; old.y += r1;
  *xp = old;
}

extern "C" void kernel_launch(void* const* d_in, const int* in_sizes, int n_in,
                              void* d_out, int out_size, void* d_ws, size_t ws_size,
                              hipStream_t stream) {
  const float* x        = (const float*)d_in[0];
  const float* Wq       = (const float*)d_in[3];
  const float* Wkv      = (const float*)d_in[4];
  const float* an_bias  = (const float*)d_in[5];
  const float* na_bias  = (const float*)d_in[6];
  const float* ah_bias  = (const float*)d_in[7];
  const float* aw_bias  = (const float*)d_in[8];
  const float* ha_bias  = (const float*)d_in[9];
  const float* wa_bias  = (const float*)d_in[10];
  const float* dwc_w    = (const float*)d_in[11];
  const float* dwc_b    = (const float*)d_in[12];
  const float* bn_gamma = (const float*)d_in[13];
  const float* bn_beta  = (const float*)d_in[14];
  const float* bn_mean  = (const float*)d_in[15];
  const float* bn_var   = (const float*)d_in[16];
  const float* base_w   = (const float*)d_in[17];
  const float* spline_w = (const float*)d_in[18];
  const float* spline_s = (const float*)d_in[19];

  char* ws = (char*)d_ws;
  ushort_t* qkvb   = (ushort_t*)(ws + 0);
  ushort_t* xbf    = (ushort_t*)(ws + 86704128);
  ushort_t* wbf    = (ushort_t*)(ws + 115605504);
  ushort_t* bpackb = (ushort_t*)(ws + 117596160);
  float* agent     = (float*)(ws + 123568128);
  float* agent_v   = (float*)(ws + 127180800);
  float* abias     = (float*)(ws + 130793472);
  float* qbias     = (float*)(ws + 132022784);
  float* xf        = (float*)(ws + 133252096);
  float* out       = (float*)d_out;

  convert_x_kernel<<<dim3(2048), dim3(256), 0, stream>>>(x, xbf);
  pack_w_kernel<<<dim3(1024), dim3(256), 0, stream>>>(Wq, Wkv, wbf);
  pack_b_kernel<<<dim3(C_), dim3(256), 0, stream>>>(base_w, spline_w, spline_s, bpackb);
  bias_kernel<<<dim3((HEADS_ * AGENT_ * N_ + 255) / 256), dim3(256), 0, stream>>>(
      an_bias, na_bias, ah_bias, aw_bias, ha_bias, wa_bias, abias, qbias);
  mfma_qkv_kernel<<<dim3(1764), dim3(512), 0, stream>>>(xbf, wbf, qkvb);
  agent_pool_kernel<<<dim3(B_ * AGENT_), dim3(C_), 0, stream>>>(qkvb, agent);
  agent_attn_mfma_kernel<<<dim3(B_ * HEADS_), dim3(256), 0, stream>>>(
      agent, qkvb, abias, agent_v);
  q_attn_kernel<<<dim3(4, HEADS_, B_), dim3(256), 0, stream>>>(
      qkvb, agent, agent_v, qbias, xf);
  dwc_kernel<<<dim3(M_), dim3(288), 0, stream>>>(
      qkvb, dwc_w, dwc_b, bn_gamma, bn_beta, bn_mean, bn_var, xf);
  kan_mfma_kernel<<<dim3(588), dim3(512), 0, stream>>>(xf, bpackb, out);
}